// Round 1
// baseline (1252.905 us; speedup 1.0000x reference)
//
#include <hip/hip_runtime.h>
#include <math.h>

#define B_SZ 1024
#define DNUM 100
#define NCAT 20
#define CARDN 100
#define DIM 1024
#define DHV 675
#define NTOK 121

typedef __attribute__((ext_vector_type(8))) short bf16x8;
typedef __attribute__((ext_vector_type(4))) float f32x4;
typedef __attribute__((ext_vector_type(4))) unsigned int uintx4;
typedef __attribute__((ext_vector_type(4))) unsigned short ushortx4;
typedef __attribute__((ext_vector_type(4))) float floatx4;

__device__ __forceinline__ unsigned short f2bf(float f) {
  unsigned int u = __float_as_uint(f);
  u += 0x7fff + ((u >> 16) & 1);
  return (unsigned short)(u >> 16);
}
__device__ __forceinline__ float bf2f(unsigned short b) {
  return __uint_as_float(((unsigned int)b) << 16);
}
__device__ __forceinline__ float gelu_exact(float x) {
  return 0.5f * x * (1.0f + erff(x * 0.70710678118654752f));
}
__device__ __forceinline__ float wred(float v) {
#pragma unroll
  for (int o = 32; o > 0; o >>= 1) v += __shfl_xor(v, o, 64);
  return v;
}

__device__ __forceinline__ float x_elem(int b, int t, int k,
    const float* tok_w, const float* tok_b, const float* cat_emb,
    const float* x_num, const int* x_cat)
{
  if (t < DNUM + 1) {
    float s = (t == 0) ? 1.0f : x_num[b * DNUM + (t - 1)];
    float bb = (t == 0) ? 0.0f : tok_b[(size_t)(t - 1) * DIM + k];
    return tok_w[(size_t)t * DIM + k] * s + bb;
  } else {
    int c = t - (DNUM + 1);
    int r = x_cat[b * NCAT + c] + c * CARDN;
    return cat_emb[(size_t)r * DIM + k] + tok_b[(size_t)(DNUM + c) * DIM + k];
  }
}

// ---------- per-row LN stats for x (B*NT rows of length 1024) ----------
__global__ __launch_bounds__(256)
void rowstats_x(const float* __restrict__ x_num, const int* __restrict__ x_cat,
                const float* __restrict__ tok_w, const float* __restrict__ tok_b,
                const float* __restrict__ cat_emb,
                float* __restrict__ xmean, float* __restrict__ xrstd)
{
  const int w = (blockIdx.x * 256 + threadIdx.x) >> 6;
  const int lane = threadIdx.x & 63;
  if (w >= B_SZ * NTOK) return;
  const int b = w / NTOK, t = w - b * NTOK;
  float s = 0.f, ss = 0.f;
  for (int k = lane; k < DIM; k += 64) {
    float v = x_elem(b, t, k, tok_w, tok_b, cat_emb, x_num, x_cat);
    s += v; ss += v * v;
  }
  s = wred(s); ss = wred(ss);
  if (lane == 0) {
    float m = s * (1.f / 1024.f);
    float var = ss * (1.f / 1024.f) - m * m;
    xmean[w] = m;
    xrstd[w] = rsqrtf(var + 1e-5f);
  }
}

// ---------- big GEMM: gelu(LN(x) @ W + b). VAR=0: v-half all rows; VAR=1: u-half t=0 ----------
template<int VAR>
__global__ __launch_bounds__(256)
void gemm1_ln(const float* __restrict__ x_num, const int* __restrict__ x_cat,
              const float* __restrict__ tok_w, const float* __restrict__ tok_b,
              const float* __restrict__ cat_emb,
              const float* __restrict__ ln_g, const float* __restrict__ ln_b,
              const float* __restrict__ xmean, const float* __restrict__ xrstd,
              const unsigned short* __restrict__ Wt,   // [768][1024] n-major bf16 (zero-padded)
              const float* __restrict__ lin0_b, int bias_off,
              unsigned short* __restrict__ outv,       // VAR=0: [M][680] bf16
              float* __restrict__ outu)                // VAR=1: [1024][680] f32
{
  __shared__ unsigned short As[128][40];
  __shared__ unsigned short Bs[128][40];
  const int tid = threadIdx.x;
  const int lane = tid & 63;
  const int wv = tid >> 6;
  const int m0 = blockIdx.x * 128;
  const int n0 = blockIdx.y * 128;

  const int ar = tid >> 1;
  const int akc = (tid & 1) << 4;
  const int am = m0 + ar;
  int b_, t_;
  if (VAR == 0) { b_ = am / NTOK; t_ = am - b_ * NTOK; }
  else { b_ = am; t_ = 0; }
  const int srow = b_ * NTOK + t_;
  const float mean = xmean[srow];
  const float rstd = xrstd[srow];
  const float* arow;
  const float* abias;
  float ascale;
  if (t_ < DNUM + 1) {
    arow = tok_w + (size_t)t_ * DIM;
    ascale = (t_ == 0) ? 1.0f : x_num[b_ * DNUM + (t_ - 1)];
    abias = (t_ == 0) ? nullptr : (tok_b + (size_t)(t_ - 1) * DIM);
  } else {
    const int c = t_ - (DNUM + 1);
    arow = cat_emb + (size_t)(x_cat[b_ * NCAT + c] + c * CARDN) * DIM;
    ascale = 1.0f;
    abias = tok_b + (size_t)(DNUM + c) * DIM;
  }
  const unsigned short* brow = Wt + (size_t)(n0 + ar) * 1024;

  const int wr = (wv >> 1) << 6;
  const int wc = (wv & 1) << 6;
  const int fr = lane & 15;
  const int fq = lane >> 4;

  f32x4 acc[4][4] = {};

  for (int k0 = 0; k0 < 1024; k0 += 32) {
    __syncthreads();
#pragma unroll
    for (int j = 0; j < 16; j += 4) {
      const int k = k0 + akc + j;
      floatx4 w = *(const floatx4*)(arow + k);
      floatx4 g = *(const floatx4*)(ln_g + k);
      floatx4 lb = *(const floatx4*)(ln_b + k);
      floatx4 bb;
      if (abias) bb = *(const floatx4*)(abias + k);
      else { bb[0]=0.f; bb[1]=0.f; bb[2]=0.f; bb[3]=0.f; }
      ushortx4 pk;
#pragma unroll
      for (int q = 0; q < 4; q++) {
        float xv = w[q] * ascale + bb[q];
        pk[q] = f2bf((xv - mean) * rstd * g[q] + lb[q]);
      }
      *(ushortx4*)&As[ar][akc + j] = pk;
    }
#pragma unroll
    for (int j = 0; j < 16; j += 8) {
      *(uintx4*)&Bs[ar][akc + j] = *(const uintx4*)(brow + k0 + akc + j);
    }
    __syncthreads();
    bf16x8 af[4], bw[4];
#pragma unroll
    for (int i = 0; i < 4; i++) {
      af[i] = *(const bf16x8*)&As[wr + i * 16 + fr][fq * 8];
      bw[i] = *(const bf16x8*)&Bs[wc + i * 16 + fr][fq * 8];
    }
#pragma unroll
    for (int i = 0; i < 4; i++)
#pragma unroll
      for (int j2 = 0; j2 < 4; j2++)
        acc[i][j2] = __builtin_amdgcn_mfma_f32_16x16x32_bf16(af[i], bw[j2], acc[i][j2], 0, 0, 0);
  }

#pragma unroll
  for (int i = 0; i < 4; i++)
#pragma unroll
    for (int j2 = 0; j2 < 4; j2++) {
      const int n = n0 + wc + j2 * 16 + fr;
      if (n >= DHV) continue;
      const float bias = lin0_b[bias_off + n];
#pragma unroll
      for (int q = 0; q < 4; q++) {
        const int m = m0 + wr + i * 16 + fq * 4 + q;
        float val = gelu_exact(acc[i][j2][q] + bias);
        if (VAR == 0) outv[(size_t)m * 680 + n] = f2bf(val);
        else outu[(size_t)m * 680 + n] = val;
      }
    }
}

// ---------- LN stats over hv rows (675 wide) ----------
__global__ __launch_bounds__(256)
void rowstats_hv(const unsigned short* __restrict__ hv,
                 float* __restrict__ vmean, float* __restrict__ vrstd)
{
  const int w = (blockIdx.x * 256 + threadIdx.x) >> 6;
  const int lane = threadIdx.x & 63;
  if (w >= B_SZ * NTOK) return;
  const unsigned short* row = hv + (size_t)w * 680;
  float s = 0.f, ss = 0.f;
  for (int k = lane; k < DHV; k += 64) { float v = bf2f(row[k]); s += v; ss += v * v; }
  s = wred(s); ss = wred(ss);
  if (lane == 0) {
    float m = s / (float)DHV;
    float var = ss / (float)DHV - m * m;
    vmean[w] = m;
    vrstd[w] = rsqrtf(var + 1e-5f);
  }
}

// ---------- token mix (sgu row 0) + u*v, pad to 704 ----------
__global__ __launch_bounds__(256)
void mix_uv(const unsigned short* __restrict__ hv,
            const float* __restrict__ vmean, const float* __restrict__ vrstd,
            const float* __restrict__ u0,
            const float* __restrict__ sgu_ln_g, const float* __restrict__ sgu_ln_b,
            const float* __restrict__ sgu_w, const float* __restrict__ sgu_b,
            unsigned short* __restrict__ uv)
{
  const int idx = blockIdx.x * 256 + threadIdx.x;
  if (idx >= B_SZ * 704) return;
  const int b = idx / 704;
  const int d = idx - b * 704;
  if (d >= DHV) { uv[idx] = 0; return; }
  float acc = 0.f, wsum = 0.f;
  const int mb = b * NTOK;
  for (int t = 0; t < NTOK; t++) {
    const float wt = sgu_w[t];                 // row s=0
    const float h = bf2f(hv[(size_t)(mb + t) * 680 + d]);
    acc += (h - vmean[mb + t]) * vrstd[mb + t] * wt;
    wsum += wt;
  }
  float v0 = sgu_ln_g[d] * acc + sgu_ln_b[d] * wsum + sgu_b[0];
  uv[idx] = f2bf(u0[(size_t)b * 680 + d] * v0);
}

// ---------- generic bf16 GEMM: A[M][lda] x Wt[N][K] ----------
template<int EPI>  // 0: +bias+extra -> f32 out; 1: relu(+bias) -> bf16 out
__global__ __launch_bounds__(256)
void gemm_bf(const unsigned short* __restrict__ A, int lda,
             const unsigned short* __restrict__ Wt, int K,
             const float* __restrict__ bias, const float* __restrict__ extra,
             int Nvalid, int ldo,
             float* __restrict__ outf, unsigned short* __restrict__ outb)
{
  __shared__ unsigned short As[128][40];
  __shared__ unsigned short Bs[128][40];
  const int tid = threadIdx.x;
  const int lane = tid & 63;
  const int wv = tid >> 6;
  const int m0 = blockIdx.x * 128;
  const int n0 = blockIdx.y * 128;
  const int ar = tid >> 1;
  const int akc = (tid & 1) << 4;
  const unsigned short* arow = A + (size_t)(m0 + ar) * lda;
  const unsigned short* brow = Wt + (size_t)(n0 + ar) * K;
  const int wr = (wv >> 1) << 6;
  const int wc = (wv & 1) << 6;
  const int fr = lane & 15;
  const int fq = lane >> 4;
  f32x4 acc[4][4] = {};
  for (int k0 = 0; k0 < K; k0 += 32) {
    __syncthreads();
#pragma unroll
    for (int j = 0; j < 16; j += 8) {
      *(uintx4*)&As[ar][akc + j] = *(const uintx4*)(arow + k0 + akc + j);
      *(uintx4*)&Bs[ar][akc + j] = *(const uintx4*)(brow + k0 + akc + j);
    }
    __syncthreads();
    bf16x8 af[4], bw[4];
#pragma unroll
    for (int i = 0; i < 4; i++) {
      af[i] = *(const bf16x8*)&As[wr + i * 16 + fr][fq * 8];
      bw[i] = *(const bf16x8*)&Bs[wc + i * 16 + fr][fq * 8];
    }
#pragma unroll
    for (int i = 0; i < 4; i++)
#pragma unroll
      for (int j2 = 0; j2 < 4; j2++)
        acc[i][j2] = __builtin_amdgcn_mfma_f32_16x16x32_bf16(af[i], bw[j2], acc[i][j2], 0, 0, 0);
  }
#pragma unroll
  for (int i = 0; i < 4; i++)
#pragma unroll
    for (int j2 = 0; j2 < 4; j2++) {
      const int n = n0 + wc + j2 * 16 + fr;
      if (n >= Nvalid) continue;
#pragma unroll
      for (int q = 0; q < 4; q++) {
        const int m = m0 + wr + i * 16 + fq * 4 + q;
        float val = acc[i][j2][q] + bias[n];
        if (EPI == 0) { val += extra[n]; outf[(size_t)m * ldo + n] = val; }
        else { val = fmaxf(val, 0.f); outb[(size_t)m * ldo + n] = f2bf(val); }
      }
    }
}

// ---------- LN + gelu -> hidden (f32 + bf16) ----------
__global__ __launch_bounds__(256)
void ln_gelu_hidden(const float* __restrict__ xfin,
                    const float* __restrict__ ln_g, const float* __restrict__ ln_b,
                    float* __restrict__ hid_f, unsigned short* __restrict__ hid_bf)
{
  const int w = (blockIdx.x * 256 + threadIdx.x) >> 6;
  const int lane = threadIdx.x & 63;
  if (w >= B_SZ) return;
  const float* row = xfin + (size_t)w * 1024;
  float s = 0.f, ss = 0.f;
  for (int k = lane; k < 1024; k += 64) { float v = row[k]; s += v; ss += v * v; }
  s = wred(s); ss = wred(ss);
  float m = s * (1.f / 1024.f);
  float var = ss * (1.f / 1024.f) - m * m;
  float rs = rsqrtf(var + 1e-5f);
  for (int k = lane; k < 1024; k += 64) {
    float v = gelu_exact((row[k] - m) * rs * ln_g[k] + ln_b[k]);
    hid_f[(size_t)w * 1024 + k] = v;
    hid_bf[(size_t)w * 1024 + k] = f2bf(v);
  }
}

// ---------- transpose + pad weights to bf16 [Npad][Kp] ----------
__global__ __launch_bounds__(256)
void tpad(const float* __restrict__ in, unsigned short* __restrict__ out,
          int ldin, int coff, int Nsrc, int Ksrc, int Kp, int total)
{
  int idx = blockIdx.x * 256 + threadIdx.x;
  if (idx >= total) return;
  int n = idx / Kp, k = idx - n * Kp;
  float v = 0.f;
  if (n < Nsrc && k < Ksrc) v = in[(size_t)k * ldin + coff + n];
  out[idx] = f2bf(v);
}

__global__ __launch_bounds__(256)
void prep_bcat(const float* __restrict__ r_b1, const float* __restrict__ a_b1,
               const float* __restrict__ gh_b1, const float* __restrict__ ex_b1,
               float* __restrict__ bcat)
{
  int n = blockIdx.x * 256 + threadIdx.x;
  if (n >= 3072) return;
  float v;
  if (n < 256) v = r_b1[n];
  else if (n < 512) v = a_b1[n - 256];
  else if (n < 1024) v = gh_b1[n - 512];
  else v = ex_b1[n - 1024];
  bcat[n] = v;
}

// ---------- per-row finale: second-layer dots + softmax/top2/combine ----------
__global__ __launch_bounds__(256)
void final_head(const unsigned short* __restrict__ H1, const float* __restrict__ hid_f,
                const float* __restrict__ r_w2, const float* __restrict__ r_b2,
                const float* __restrict__ a_w2, const float* __restrict__ a_b2,
                const float* __restrict__ gh_w2, const float* __restrict__ gh_b2,
                const float* __restrict__ ex_w2, const float* __restrict__ ex_b2,
                const float* __restrict__ base_w, const float* __restrict__ base_b,
                float* __restrict__ out)
{
  const int b = blockIdx.x;
  const int tid = threadIdx.x;
  const unsigned short* h1 = H1 + (size_t)b * 3072;
  float p[11];
#pragma unroll
  for (int i = 0; i < 11; i++) p[i] = 0.f;
  {
    const int m = tid;  // 256 threads == 256 elements
    float hr = bf2f(h1[m]);
    p[0] = hr * r_w2[m * 4 + 0];
    p[1] = hr * r_w2[m * 4 + 1];
    p[2] = hr * r_w2[m * 4 + 2];
    p[3] = hr * r_w2[m * 4 + 3];
    float ha = bf2f(h1[256 + m]);
    p[4] = ha * a_w2[m];
  }
  for (int m = tid; m < 512; m += 256) {
    p[5] += bf2f(h1[512 + m]) * gh_w2[m];
#pragma unroll
    for (int e = 0; e < 4; e++)
      p[6 + e] += bf2f(h1[1024 + e * 512 + m]) * ex_w2[e * 512 + m];
  }
  for (int k = tid; k < 1024; k += 256) p[10] += hid_f[(size_t)b * 1024 + k] * base_w[k];

  __shared__ float red[11][4];
  const int lane = tid & 63, wv = tid >> 6;
#pragma unroll
  for (int i = 0; i < 11; i++) {
    float v = wred(p[i]);
    if (lane == 0) red[i][wv] = v;
  }
  __syncthreads();
  if (tid == 0) {
    float s[11];
#pragma unroll
    for (int i = 0; i < 11; i++) s[i] = red[i][0] + red[i][1] + red[i][2] + red[i][3];
    float lg[4];
#pragma unroll
    for (int e = 0; e < 4; e++) lg[e] = s[e] + r_b2[e];
    float mx = fmaxf(fmaxf(lg[0], lg[1]), fmaxf(lg[2], lg[3]));
    float den[4]; float dsum = 0.f;
#pragma unroll
    for (int e = 0; e < 4; e++) { den[e] = expf(lg[e] - mx); dsum += den[e]; }
#pragma unroll
    for (int e = 0; e < 4; e++) den[e] /= dsum;
    int i1 = 0;
    for (int e = 1; e < 4; e++) if (den[e] > den[i1]) i1 = e;
    int i2 = -1;
    for (int e = 0; e < 4; e++) { if (e == i1) continue; if (i2 < 0 || den[e] > den[i2]) i2 = e; }
    float eo[4];
#pragma unroll
    for (int e = 0; e < 4; e++) eo[e] = s[6 + e] + ex_b2[e];
    float v1 = den[i1], v2 = den[i2];
    float ssum = fmaxf(v1 + v2, 1e-8f);
    float local = (v1 * eo[i1] + v2 * eo[i2]) / ssum;
    float glob = s[5] + gh_b2[0];
    float alpha = 1.0f / (1.0f + expf(-(s[4] + a_b2[0])));
    out[b] = s[10] + base_b[0] + alpha * (glob + local);
  }
}

extern "C" void kernel_launch(void* const* d_in, const int* in_sizes, int n_in,
                              void* d_out, int out_size, void* d_ws, size_t ws_size,
                              hipStream_t stream)
{
  const float* x_num  = (const float*)d_in[0];
  const int*   x_cat  = (const int*)d_in[1];
  const float* tok_w  = (const float*)d_in[2];
  const float* tok_b  = (const float*)d_in[3];
  const float* cat_emb= (const float*)d_in[4];
  const float* ln_g   = (const float*)d_in[5];
  const float* ln_b   = (const float*)d_in[6];
  const float* lin0_w = (const float*)d_in[7];
  const float* lin0_b = (const float*)d_in[8];
  const float* sgu_ln_g = (const float*)d_in[9];
  const float* sgu_ln_b = (const float*)d_in[10];
  const float* sgu_w  = (const float*)d_in[11];
  const float* sgu_b  = (const float*)d_in[12];
  const float* lin1_w = (const float*)d_in[13];
  const float* lin1_b = (const float*)d_in[14];
  const float* r_w1   = (const float*)d_in[15];
  const float* r_b1   = (const float*)d_in[16];
  const float* r_w2   = (const float*)d_in[17];
  const float* r_b2   = (const float*)d_in[18];
  const float* a_w1   = (const float*)d_in[19];
  const float* a_b1   = (const float*)d_in[20];
  const float* a_w2   = (const float*)d_in[21];
  const float* a_b2   = (const float*)d_in[22];
  const float* base_w = (const float*)d_in[23];
  const float* base_b = (const float*)d_in[24];
  const float* gh_w1  = (const float*)d_in[25];
  const float* gh_b1  = (const float*)d_in[26];
  const float* gh_w2  = (const float*)d_in[27];
  const float* gh_b2  = (const float*)d_in[28];
  const float* ex_w1  = (const float*)d_in[29];
  const float* ex_b1  = (const float*)d_in[30];
  const float* ex_w2  = (const float*)d_in[31];
  const float* ex_b2  = (const float*)d_in[32];
  (void)in_sizes; (void)n_in; (void)out_size; (void)ws_size;

  char* ws = (char*)d_ws;
  size_t off = 0;
  auto alloc = [&](size_t bytes) { void* p = ws + off; off += (bytes + 255) & ~(size_t)255; return p; };
  const int M = B_SZ * NTOK;  // 123904 = 968*128
  unsigned short* hv   = (unsigned short*)alloc((size_t)M * 680 * 2);
  float* u0            = (float*)alloc((size_t)1024 * 680 * 4);
  float* xmean         = (float*)alloc((size_t)M * 4);
  float* xrstd         = (float*)alloc((size_t)M * 4);
  float* vmean         = (float*)alloc((size_t)M * 4);
  float* vrstd         = (float*)alloc((size_t)M * 4);
  unsigned short* uv   = (unsigned short*)alloc((size_t)1024 * 704 * 2);
  float* xfin          = (float*)alloc((size_t)1024 * 1024 * 4);
  float* hid_f         = (float*)alloc((size_t)1024 * 1024 * 4);
  unsigned short* hidb = (unsigned short*)alloc((size_t)1024 * 1024 * 2);
  unsigned short* H1   = (unsigned short*)alloc((size_t)1024 * 3072 * 2);
  unsigned short* w0v  = (unsigned short*)alloc((size_t)768 * 1024 * 2);
  unsigned short* w0u  = (unsigned short*)alloc((size_t)768 * 1024 * 2);
  unsigned short* w1t  = (unsigned short*)alloc((size_t)1024 * 704 * 2);
  unsigned short* wcat = (unsigned short*)alloc((size_t)3072 * 1024 * 2);
  float* bcat          = (float*)alloc((size_t)3072 * 4);

  dim3 blk(256);
  // weight prep (bf16, transposed to [n][k], zero padded)
  tpad<<<(768 * 1024 + 255) / 256, blk, 0, stream>>>(lin0_w, w0v, 1350, 675, 675, 1024, 1024, 768 * 1024);
  tpad<<<(768 * 1024 + 255) / 256, blk, 0, stream>>>(lin0_w, w0u, 1350, 0, 675, 1024, 1024, 768 * 1024);
  tpad<<<(1024 * 704 + 255) / 256, blk, 0, stream>>>(lin1_w, w1t, 1024, 0, 1024, 675, 704, 1024 * 704);
  tpad<<<(256 * 1024 + 255) / 256, blk, 0, stream>>>(r_w1, wcat, 256, 0, 256, 1024, 1024, 256 * 1024);
  tpad<<<(256 * 1024 + 255) / 256, blk, 0, stream>>>(a_w1, wcat + 256 * 1024, 256, 0, 256, 1024, 1024, 256 * 1024);
  tpad<<<(512 * 1024 + 255) / 256, blk, 0, stream>>>(gh_w1, wcat + 512 * 1024, 512, 0, 512, 1024, 1024, 512 * 1024);
  for (int e = 0; e < 4; e++)
    tpad<<<(512 * 1024 + 255) / 256, blk, 0, stream>>>(ex_w1 + (size_t)e * 1024 * 512,
        wcat + (size_t)(1024 + e * 512) * 1024, 512, 0, 512, 1024, 1024, 512 * 1024);
  prep_bcat<<<(3072 + 255) / 256, blk, 0, stream>>>(r_b1, a_b1, gh_b1, ex_b1, bcat);

  rowstats_x<<<M / 4, blk, 0, stream>>>(x_num, x_cat, tok_w, tok_b, cat_emb, xmean, xrstd);

  gemm1_ln<0><<<dim3(M / 128, 6), blk, 0, stream>>>(x_num, x_cat, tok_w, tok_b, cat_emb,
      ln_g, ln_b, xmean, xrstd, w0v, lin0_b, DHV, hv, nullptr);
  gemm1_ln<1><<<dim3(8, 6), blk, 0, stream>>>(x_num, x_cat, tok_w, tok_b, cat_emb,
      ln_g, ln_b, xmean, xrstd, w0u, lin0_b, 0, nullptr, u0);

  rowstats_hv<<<M / 4, blk, 0, stream>>>(hv, vmean, vrstd);
  mix_uv<<<(B_SZ * 704) / 256, blk, 0, stream>>>(hv, vmean, vrstd, u0, sgu_ln_g, sgu_ln_b, sgu_w, sgu_b, uv);

  gemm_bf<0><<<dim3(8, 8), blk, 0, stream>>>(uv, 704, w1t, 704, lin1_b, tok_w, 1024, 1024, xfin, nullptr);
  ln_gelu_hidden<<<B_SZ / 4, blk, 0, stream>>>(xfin, ln_g, ln_b, hid_f, hidb);
  gemm_bf<1><<<dim3(8, 24), blk, 0, stream>>>(hidb, 1024, wcat, 1024, bcat, nullptr, 3072, 3072, nullptr, H1);

  final_head<<<B_SZ, blk, 0, stream>>>(H1, hid_f, r_w2, r_b2, a_w2, a_b2, gh_w2, gh_b2,
                                       ex_w2, ex_b2, base_w, base_b, (float*)d_out);
}

// Round 2
// 884.935 us; speedup vs baseline: 1.4158x; 1.4158x over previous
//
#include <hip/hip_runtime.h>
#include <math.h>

#define B_SZ 1024
#define NTOK 121
#define CH_B 256
#define CH_ROWS (CH_B * NTOK)   // 30976 = 242*128
#define CH_MB 242
#define NCHUNK 4

typedef __attribute__((ext_vector_type(8))) short bf16x8;
typedef __attribute__((ext_vector_type(4))) float f32x4;
typedef __attribute__((ext_vector_type(4))) float floatx4;
typedef __attribute__((ext_vector_type(4))) unsigned short ushortx4;
typedef __attribute__((ext_vector_type(8))) unsigned short ushortx8;

#define GLOAD16(src, dst) __builtin_amdgcn_global_load_lds( \
    (const __attribute__((address_space(1))) void*)(src), \
    (__attribute__((address_space(3))) void*)(dst), 16, 0, 0)

__device__ __forceinline__ unsigned short f2bf(float f) {
  unsigned int u = __float_as_uint(f);
  u += 0x7fff + ((u >> 16) & 1);
  return (unsigned short)(u >> 16);
}
__device__ __forceinline__ float bf2f(unsigned short b) {
  return __uint_as_float(((unsigned int)b) << 16);
}
__device__ __forceinline__ float gelu_exact(float x) {
  return 0.5f * x * (1.0f + erff(x * 0.70710678118654752f));
}
__device__ __forceinline__ float wred(float v) {
#pragma unroll
  for (int o = 32; o > 0; o >>= 1) v += __shfl_xor(v, o, 64);
  return v;
}

// ---------------- build xln = bf16(LN(x)) ; also compact t=0 rows ----------------
__global__ __launch_bounds__(256)
void build_xln(const float* __restrict__ x_num, const int* __restrict__ x_cat,
               const float* __restrict__ tok_w, const float* __restrict__ tok_b,
               const float* __restrict__ cat_emb,
               const float* __restrict__ ln_g, const float* __restrict__ ln_b,
               int b0, unsigned short* __restrict__ xc, unsigned short* __restrict__ xln0)
{
  const int w = blockIdx.x;                 // 0..CH_ROWS-1
  const int bl = w / NTOK, t = w - bl * NTOK;
  const int b = b0 + bl;
  const int c = threadIdx.x * 4;
  const int lane = threadIdx.x & 63, wv = threadIdx.x >> 6;

  const float* wrow;
  float scale = 1.f;
  const float* brow = nullptr;
  if (t == 0) {
    wrow = tok_w;
  } else if (t < 101) {
    wrow = tok_w + (size_t)t * 1024;
    scale = x_num[b * 100 + (t - 1)];
    brow = tok_b + (size_t)(t - 1) * 1024;
  } else {
    const int cc = t - 101;
    wrow = cat_emb + (size_t)(x_cat[b * 20 + cc] + cc * 100) * 1024;
    brow = tok_b + (size_t)(t - 1) * 1024;
  }
  floatx4 wv4 = *(const floatx4*)(wrow + c);
  floatx4 bb;
  if (brow) bb = *(const floatx4*)(brow + c);
  else { bb[0]=0.f; bb[1]=0.f; bb[2]=0.f; bb[3]=0.f; }
  float v[4];
#pragma unroll
  for (int q = 0; q < 4; q++) v[q] = wv4[q] * scale + bb[q];

  float s = v[0] + v[1] + v[2] + v[3];
  float ss = v[0]*v[0] + v[1]*v[1] + v[2]*v[2] + v[3]*v[3];
  s = wred(s); ss = wred(ss);
  __shared__ float sh[2][4];
  if (lane == 0) { sh[0][wv] = s; sh[1][wv] = ss; }
  __syncthreads();
  const float S  = sh[0][0] + sh[0][1] + sh[0][2] + sh[0][3];
  const float SS = sh[1][0] + sh[1][1] + sh[1][2] + sh[1][3];
  const float m = S * (1.f / 1024.f);
  const float var = SS * (1.f / 1024.f) - m * m;
  const float rs = rsqrtf(var + 1e-5f);

  floatx4 g = *(const floatx4*)(ln_g + c);
  floatx4 lb = *(const floatx4*)(ln_b + c);
  ushortx4 o;
#pragma unroll
  for (int q = 0; q < 4; q++) o[q] = f2bf((v[q] - m) * rs * g[q] + lb[q]);
  *(ushortx4*)(xc + (size_t)w * 1024 + c) = o;
  if (t == 0) *(ushortx4*)(xln0 + (size_t)b * 1024 + c) = o;
}

// ---------------- generic bf16 GEMM, m97 structure (global_load_lds staging) ----------------
// A [M][pitchA] bf16, Bw [NB*128][K] bf16 (n-major). Tile 128x128, BK=32.
// EPI 0: f32 out = acc + bias[n] + extra[n]
// EPI 1: bf16 out = relu(acc + bias[n])
// EPI 2: bf16 out = gelu(acc + bias[bias_off+n]) for n<Nvalid, 0 for Nvalid<=n<ldo
template<int EPI>
__global__ __launch_bounds__(256)
void gemm_gl(const unsigned short* __restrict__ A, long pitchA,
             const unsigned short* __restrict__ Bw, int K,
             const float* __restrict__ bias, int bias_off,
             const float* __restrict__ extra,
             int NB, int Nvalid, int ldo,
             float* __restrict__ outf, unsigned short* __restrict__ outb)
{
  __shared__ unsigned short As[128 * 32];
  __shared__ unsigned short Bs[128 * 32];
  const int tid = threadIdx.x, lane = tid & 63, wv = tid >> 6;
  const int bid = blockIdx.x;
  const int nb = bid % NB, mb = bid / NB;
  const int m0 = mb * 128, n0 = nb * 128;
  const int wr = (wv >> 1) << 6, wc = (wv & 1) << 6;
  const int fr = lane & 15, fq = lane >> 4;
  const int c0 = wv * 2;
  const int srow = lane >> 2;
  const int sk = (lane & 3) << 3;

  const unsigned short* a0 = A + (size_t)(m0 + c0 * 16 + srow) * pitchA + sk;
  const unsigned short* a1 = A + (size_t)(m0 + (c0 + 1) * 16 + srow) * pitchA + sk;
  const unsigned short* b0p = Bw + (size_t)(n0 + c0 * 16 + srow) * K + sk;
  const unsigned short* b1p = Bw + (size_t)(n0 + (c0 + 1) * 16 + srow) * K + sk;

  f32x4 acc[4][4] = {};
  for (int k0 = 0; k0 < K; k0 += 32) {
    __syncthreads();
    GLOAD16(a0 + k0, &As[c0 * 512]);
    GLOAD16(a1 + k0, &As[(c0 + 1) * 512]);
    GLOAD16(b0p + k0, &Bs[c0 * 512]);
    GLOAD16(b1p + k0, &Bs[(c0 + 1) * 512]);
    __syncthreads();
    bf16x8 af[4], bw_[4];
#pragma unroll
    for (int i = 0; i < 4; i++) {
      af[i]  = *(const bf16x8*)&As[(wr + i * 16 + fr) * 32 + fq * 8];
      bw_[i] = *(const bf16x8*)&Bs[(wc + i * 16 + fr) * 32 + fq * 8];
    }
#pragma unroll
    for (int i = 0; i < 4; i++)
#pragma unroll
      for (int j = 0; j < 4; j++)
        acc[i][j] = __builtin_amdgcn_mfma_f32_16x16x32_bf16(af[i], bw_[j], acc[i][j], 0, 0, 0);
  }

#pragma unroll
  for (int i = 0; i < 4; i++)
#pragma unroll
    for (int j = 0; j < 4; j++) {
      const int n = n0 + wc + j * 16 + fr;
      if (n >= ldo) continue;
      const bool valid = (n < Nvalid);
      const float bv = valid ? bias[bias_off + n] : 0.f;
      const float ev = (EPI == 0) ? extra[n] : 0.f;
#pragma unroll
      for (int q = 0; q < 4; q++) {
        const int m = m0 + wr + i * 16 + fq * 4 + q;
        const float a = acc[i][j][q];
        if (EPI == 0) {
          outf[(size_t)m * ldo + n] = a + bv + ev;
        } else if (EPI == 1) {
          outb[(size_t)m * ldo + n] = f2bf(fmaxf(a + bv, 0.f));
        } else {
          outb[(size_t)m * ldo + n] = valid ? f2bf(gelu_exact(a + bv)) : (unsigned short)0;
        }
      }
    }
}

// ---------------- LN stats over hv rows (675 valid of 704) ----------------
__global__ __launch_bounds__(256)
void rowstats_hv(const unsigned short* __restrict__ hv,
                 float* __restrict__ vmean, float* __restrict__ vrstd, int nrows)
{
  const int w = blockIdx.x * 4 + (threadIdx.x >> 6);
  const int lane = threadIdx.x & 63;
  if (w >= nrows) return;
  const unsigned short* row = hv + (size_t)w * 704;
  float s = 0.f, ss = 0.f;
  for (int c = lane; c < 88; c += 64) {
    bf16x8 h = *(const bf16x8*)(row + c * 8);
#pragma unroll
    for (int q = 0; q < 8; q++) { float f = bf2f((unsigned short)h[q]); s += f; ss += f * f; }
  }
  s = wred(s); ss = wred(ss);
  if (lane == 0) {
    const float m = s * (1.f / 675.f);
    const float var = ss * (1.f / 675.f) - m * m;
    vmean[w] = m;
    vrstd[w] = rsqrtf(var + 1e-5f);
  }
}

// ---------------- token mix (sgu row 0) -> v0 rows ----------------
__global__ __launch_bounds__(256)
void mix_v(const unsigned short* __restrict__ hv,
           const float* __restrict__ vmean, const float* __restrict__ vrstd,
           const float* __restrict__ sgu_ln_g, const float* __restrict__ sgu_ln_b,
           const float* __restrict__ sgu_w, const float* __restrict__ sgu_b,
           int b0, unsigned short* __restrict__ v0)
{
  const int idx = blockIdx.x * 256 + threadIdx.x;   // CH_B * 88
  const int bl = idx / 88, c8 = idx - bl * 88;
  const int d = c8 * 8;
  float acc[8] = {0.f,0.f,0.f,0.f,0.f,0.f,0.f,0.f};
  float wsum = 0.f;
  const unsigned short* base = hv + (size_t)bl * NTOK * 704 + d;
  const int rbase = bl * NTOK;
  for (int t = 0; t < NTOK; t++) {
    const float wt = sgu_w[t];
    const float mu = vmean[rbase + t];
    const float crho = wt * vrstd[rbase + t];
    bf16x8 h = *(const bf16x8*)(base + (size_t)t * 704);
#pragma unroll
    for (int q = 0; q < 8; q++) acc[q] += (bf2f((unsigned short)h[q]) - mu) * crho;
    wsum += wt;
  }
  const float sb = sgu_b[0];
  ushortx8 o;
#pragma unroll
  for (int q = 0; q < 8; q++) {
    const int dd = d + q;
    float val = 0.f;
    if (dd < 675) val = sgu_ln_g[dd] * acc[q] + sgu_ln_b[dd] * wsum + sb;
    o[q] = (dd < 675) ? f2bf(val) : (unsigned short)0;
  }
  *(ushortx8*)(v0 + (size_t)(b0 + bl) * 704 + d) = o;
}

// ---------------- uv = u0 * v0 (bf16, 8-wide) ----------------
__global__ __launch_bounds__(256)
void mul_uv(const unsigned short* __restrict__ u0, const unsigned short* __restrict__ v0,
            unsigned short* __restrict__ uv)
{
  const int idx = blockIdx.x * 256 + threadIdx.x;   // 1024*88
  if (idx >= 1024 * 88) return;
  bf16x8 a = *(const bf16x8*)(u0 + (size_t)idx * 8);
  bf16x8 b = *(const bf16x8*)(v0 + (size_t)idx * 8);
  ushortx8 o;
#pragma unroll
  for (int q = 0; q < 8; q++) o[q] = f2bf(bf2f((unsigned short)a[q]) * bf2f((unsigned short)b[q]));
  *(ushortx8*)(uv + (size_t)idx * 8) = o;
}

// ---------------- LN + gelu -> hidden (f32 + bf16) ----------------
__global__ __launch_bounds__(256)
void ln_gelu_hidden(const float* __restrict__ xfin,
                    const float* __restrict__ ln_g, const float* __restrict__ ln_b,
                    float* __restrict__ hid_f, unsigned short* __restrict__ hid_bf)
{
  const int w = (blockIdx.x * 256 + threadIdx.x) >> 6;
  const int lane = threadIdx.x & 63;
  if (w >= B_SZ) return;
  const float* row = xfin + (size_t)w * 1024;
  float s = 0.f, ss = 0.f;
  for (int k = lane; k < 1024; k += 64) { float v = row[k]; s += v; ss += v * v; }
  s = wred(s); ss = wred(ss);
  const float m = s * (1.f / 1024.f);
  const float var = ss * (1.f / 1024.f) - m * m;
  const float rs = rsqrtf(var + 1e-5f);
  for (int k = lane; k < 1024; k += 64) {
    float v = gelu_exact((row[k] - m) * rs * ln_g[k] + ln_b[k]);
    hid_f[(size_t)w * 1024 + k] = v;
    hid_bf[(size_t)w * 1024 + k] = f2bf(v);
  }
}

// ---------------- tiled transpose f32[k][n] -> bf16[n][k] (zero padded) ----------------
__global__ __launch_bounds__(256)
void tpadT(const float* __restrict__ in, unsigned short* __restrict__ out,
           int ldin, int coff, int Nsrc, int Ksrc, int Kp)
{
  __shared__ float tile[64][65];
  const int kx = threadIdx.x;       // 0..63
  const int ry = threadIdx.y;       // 0..3
  const int k0 = blockIdx.x * 64;
  const int n0 = blockIdx.y * 64;
  for (int r = ry; r < 64; r += 4) {
    const int k = k0 + r;
    const int n = n0 + kx;
    tile[r][kx] = (k < Ksrc && n < Nsrc) ? in[(size_t)k * ldin + coff + n] : 0.f;
  }
  __syncthreads();
  for (int r = ry; r < 64; r += 4) {
    const int n = n0 + r;
    const int k = k0 + kx;
    out[(size_t)n * Kp + k] = f2bf(tile[kx][r]);
  }
}

__global__ __launch_bounds__(256)
void prep_bcat(const float* __restrict__ r_b1, const float* __restrict__ a_b1,
               const float* __restrict__ gh_b1, const float* __restrict__ ex_b1,
               float* __restrict__ bcat)
{
  const int n = blockIdx.x * 256 + threadIdx.x;
  if (n >= 3072) return;
  float v;
  if (n < 256) v = r_b1[n];
  else if (n < 512) v = a_b1[n - 256];
  else if (n < 1024) v = gh_b1[n - 512];
  else v = ex_b1[n - 1024];
  bcat[n] = v;
}

// ---------------- per-row finale ----------------
__global__ __launch_bounds__(256)
void final_head(const unsigned short* __restrict__ H1, const float* __restrict__ hid_f,
                const float* __restrict__ r_w2, const float* __restrict__ r_b2,
                const float* __restrict__ a_w2, const float* __restrict__ a_b2,
                const float* __restrict__ gh_w2, const float* __restrict__ gh_b2,
                const float* __restrict__ ex_w2, const float* __restrict__ ex_b2,
                const float* __restrict__ base_w, const float* __restrict__ base_b,
                float* __restrict__ out)
{
  const int b = blockIdx.x;
  const int tid = threadIdx.x;
  const unsigned short* h1 = H1 + (size_t)b * 3072;
  float p[11];
#pragma unroll
  for (int i = 0; i < 11; i++) p[i] = 0.f;
  {
    const int m = tid;
    const float hr = bf2f(h1[m]);
    p[0] = hr * r_w2[m * 4 + 0];
    p[1] = hr * r_w2[m * 4 + 1];
    p[2] = hr * r_w2[m * 4 + 2];
    p[3] = hr * r_w2[m * 4 + 3];
    const float ha = bf2f(h1[256 + m]);
    p[4] = ha * a_w2[m];
  }
  for (int m = tid; m < 512; m += 256) {
    p[5] += bf2f(h1[512 + m]) * gh_w2[m];
#pragma unroll
    for (int e = 0; e < 4; e++)
      p[6 + e] += bf2f(h1[1024 + e * 512 + m]) * ex_w2[e * 512 + m];
  }
  for (int k = tid; k < 1024; k += 256) p[10] += hid_f[(size_t)b * 1024 + k] * base_w[k];

  __shared__ float red[11][4];
  const int lane = tid & 63, wv = tid >> 6;
#pragma unroll
  for (int i = 0; i < 11; i++) {
    const float v = wred(p[i]);
    if (lane == 0) red[i][wv] = v;
  }
  __syncthreads();
  if (tid == 0) {
    float s[11];
#pragma unroll
    for (int i = 0; i < 11; i++) s[i] = red[i][0] + red[i][1] + red[i][2] + red[i][3];
    float lg[4];
#pragma unroll
    for (int e = 0; e < 4; e++) lg[e] = s[e] + r_b2[e];
    const float mx = fmaxf(fmaxf(lg[0], lg[1]), fmaxf(lg[2], lg[3]));
    float den[4]; float dsum = 0.f;
#pragma unroll
    for (int e = 0; e < 4; e++) { den[e] = expf(lg[e] - mx); dsum += den[e]; }
#pragma unroll
    for (int e = 0; e < 4; e++) den[e] /= dsum;
    int i1 = 0;
    for (int e = 1; e < 4; e++) if (den[e] > den[i1]) i1 = e;
    int i2 = -1;
    for (int e = 0; e < 4; e++) { if (e == i1) continue; if (i2 < 0 || den[e] > den[i2]) i2 = e; }
    float eo[4];
#pragma unroll
    for (int e = 0; e < 4; e++) eo[e] = s[6 + e] + ex_b2[e];
    const float v1 = den[i1], v2 = den[i2];
    const float ssum = fmaxf(v1 + v2, 1e-8f);
    const float local = (v1 * eo[i1] + v2 * eo[i2]) / ssum;
    const float glob = s[5] + gh_b2[0];
    const float alpha = 1.0f / (1.0f + expf(-(s[4] + a_b2[0])));
    out[b] = s[10] + base_b[0] + alpha * (glob + local);
  }
}

extern "C" void kernel_launch(void* const* d_in, const int* in_sizes, int n_in,
                              void* d_out, int out_size, void* d_ws, size_t ws_size,
                              hipStream_t stream)
{
  const float* x_num  = (const float*)d_in[0];
  const int*   x_cat  = (const int*)d_in[1];
  const float* tok_w  = (const float*)d_in[2];
  const float* tok_b  = (const float*)d_in[3];
  const float* cat_emb= (const float*)d_in[4];
  const float* ln_g   = (const float*)d_in[5];
  const float* ln_b   = (const float*)d_in[6];
  const float* lin0_w = (const float*)d_in[7];
  const float* lin0_b = (const float*)d_in[8];
  const float* sgu_ln_g = (const float*)d_in[9];
  const float* sgu_ln_b = (const float*)d_in[10];
  const float* sgu_w  = (const float*)d_in[11];
  const float* sgu_b  = (const float*)d_in[12];
  const float* lin1_w = (const float*)d_in[13];
  const float* lin1_b = (const float*)d_in[14];
  const float* r_w1   = (const float*)d_in[15];
  const float* r_b1   = (const float*)d_in[16];
  const float* r_w2   = (const float*)d_in[17];
  const float* r_b2   = (const float*)d_in[18];
  const float* a_w1   = (const float*)d_in[19];
  const float* a_b1   = (const float*)d_in[20];
  const float* a_w2   = (const float*)d_in[21];
  const float* a_b2   = (const float*)d_in[22];
  const float* base_w = (const float*)d_in[23];
  const float* base_b = (const float*)d_in[24];
  const float* gh_w1  = (const float*)d_in[25];
  const float* gh_b1  = (const float*)d_in[26];
  const float* gh_w2  = (const float*)d_in[27];
  const float* gh_b2  = (const float*)d_in[28];
  const float* ex_w1  = (const float*)d_in[29];
  const float* ex_b1  = (const float*)d_in[30];
  const float* ex_w2  = (const float*)d_in[31];
  const float* ex_b2  = (const float*)d_in[32];
  (void)in_sizes; (void)n_in; (void)out_size; (void)ws_size;

  char* ws = (char*)d_ws;
  size_t off = 0;
  auto alloc = [&](size_t bytes) { void* p = ws + off; off += (bytes + 255) & ~(size_t)255; return p; };

  // persistent
  unsigned short* w0v  = (unsigned short*)alloc((size_t)768 * 1024 * 2);
  unsigned short* w0u  = (unsigned short*)alloc((size_t)768 * 1024 * 2);
  unsigned short* w1t  = (unsigned short*)alloc((size_t)1024 * 704 * 2);
  unsigned short* wcat = (unsigned short*)alloc((size_t)3072 * 1024 * 2);
  float* bcat          = (float*)alloc((size_t)3072 * 4);
  unsigned short* xln0 = (unsigned short*)alloc((size_t)B_SZ * 1024 * 2);
  unsigned short* u0   = (unsigned short*)alloc((size_t)B_SZ * 704 * 2);
  unsigned short* v0   = (unsigned short*)alloc((size_t)B_SZ * 704 * 2);
  unsigned short* uv   = (unsigned short*)alloc((size_t)B_SZ * 704 * 2);
  float* xfin          = (float*)alloc((size_t)B_SZ * 1024 * 4);
  float* hid_f         = (float*)alloc((size_t)B_SZ * 1024 * 4);
  unsigned short* hidb = (unsigned short*)alloc((size_t)B_SZ * 1024 * 2);
  unsigned short* H1   = (unsigned short*)alloc((size_t)B_SZ * 3072 * 2);
  // chunk-reused
  unsigned short* xln_c = (unsigned short*)alloc((size_t)CH_ROWS * 1024 * 2);
  unsigned short* hv_c  = (unsigned short*)alloc((size_t)CH_ROWS * 704 * 2);
  float* vmean_c        = (float*)alloc((size_t)CH_ROWS * 4);
  float* vrstd_c        = (float*)alloc((size_t)CH_ROWS * 4);

  const dim3 blk(256);
  const dim3 tblk(64, 4);

  // weight prep (tiled transposes, bf16, zero padded)
  tpadT<<<dim3(16, 12), tblk, 0, stream>>>(lin0_w, w0v, 1350, 675, 675, 1024, 1024);
  tpadT<<<dim3(16, 12), tblk, 0, stream>>>(lin0_w, w0u, 1350, 0, 675, 1024, 1024);
  tpadT<<<dim3(11, 16), tblk, 0, stream>>>(lin1_w, w1t, 1024, 0, 1024, 675, 704);
  tpadT<<<dim3(16, 4), tblk, 0, stream>>>(r_w1, wcat, 256, 0, 256, 1024, 1024);
  tpadT<<<dim3(16, 4), tblk, 0, stream>>>(a_w1, wcat + (size_t)256 * 1024, 256, 0, 256, 1024, 1024);
  tpadT<<<dim3(16, 8), tblk, 0, stream>>>(gh_w1, wcat + (size_t)512 * 1024, 512, 0, 512, 1024, 1024);
  for (int e = 0; e < 4; e++)
    tpadT<<<dim3(16, 8), tblk, 0, stream>>>(ex_w1 + (size_t)e * 1024 * 512,
        wcat + (size_t)(1024 + e * 512) * 1024, 512, 0, 512, 1024, 1024);
  prep_bcat<<<12, blk, 0, stream>>>(r_b1, a_b1, gh_b1, ex_b1, bcat);

  for (int c = 0; c < NCHUNK; c++) {
    const int b0 = c * CH_B;
    build_xln<<<CH_ROWS, blk, 0, stream>>>(x_num, x_cat, tok_w, tok_b, cat_emb,
                                           ln_g, ln_b, b0, xln_c, xln0);
    gemm_gl<2><<<CH_MB * 6, blk, 0, stream>>>(xln_c, 1024, w0v, 1024,
        lin0_b, 675, nullptr, 6, 675, 704, nullptr, hv_c);
    rowstats_hv<<<CH_ROWS / 4, blk, 0, stream>>>(hv_c, vmean_c, vrstd_c, CH_ROWS);
    mix_v<<<CH_B * 88 / 256, blk, 0, stream>>>(hv_c, vmean_c, vrstd_c,
        sgu_ln_g, sgu_ln_b, sgu_w, sgu_b, b0, v0);
  }

  // u half: gelu(LN(x[:,0]) @ W_u + b) for all b
  gemm_gl<2><<<8 * 6, blk, 0, stream>>>(xln0, 1024, w0u, 1024,
      lin0_b, 0, nullptr, 6, 675, 704, nullptr, u0);
  mul_uv<<<(1024 * 88 + 255) / 256, blk, 0, stream>>>(u0, v0, uv);

  // xfin = uv @ lin1_w + lin1_b + xr0  (xr0 = tok_w row 0)
  gemm_gl<0><<<8 * 8, blk, 0, stream>>>(uv, 704, w1t, 704,
      lin1_b, 0, tok_w, 8, 1024, 1024, xfin, nullptr);
  ln_gelu_hidden<<<B_SZ / 4, blk, 0, stream>>>(xfin, ln_g, ln_b, hid_f, hidb);
  // concatenated heads: relu(hidden @ [r|a|gh|ex] + b)
  gemm_gl<1><<<8 * 24, blk, 0, stream>>>(hidb, 1024, wcat, 1024,
      bcat, 0, nullptr, 24, 3072, 3072, nullptr, H1);

  final_head<<<B_SZ, blk, 0, stream>>>(H1, hid_f, r_w2, r_b2, a_w2, a_b2, gh_w2, gh_b2,
                                       ex_w2, ex_b2, base_w, base_b, (float*)d_out);
}

// Round 3
// 759.523 us; speedup vs baseline: 1.6496x; 1.1651x over previous
//
#include <hip/hip_runtime.h>
#include <math.h>

#define B_SZ 1024

typedef __attribute__((ext_vector_type(8))) short bf16x8;
typedef __attribute__((ext_vector_type(4))) float f32x4;
typedef __attribute__((ext_vector_type(4))) float floatx4;
typedef __attribute__((ext_vector_type(4))) unsigned short ushortx4;

#define GLOAD16(src, dst) __builtin_amdgcn_global_load_lds( \
    (const __attribute__((address_space(1))) void*)(src), \
    (__attribute__((address_space(3))) void*)(dst), 16, 0, 0)

__device__ __forceinline__ unsigned short f2bf(float f) {
  unsigned int u = __float_as_uint(f);
  u += 0x7fff + ((u >> 16) & 1);
  return (unsigned short)(u >> 16);
}
__device__ __forceinline__ float bf2f(unsigned short b) {
  return __uint_as_float(((unsigned int)b) << 16);
}
__device__ __forceinline__ float gelu_exact(float x) {
  return 0.5f * x * (1.0f + erff(x * 0.70710678118654752f));
}
__device__ __forceinline__ float wred(float v) {
#pragma unroll
  for (int o = 32; o > 0; o >>= 1) v += __shfl_xor(v, o, 64);
  return v;
}

// ---------------- tiled transpose f32[k][n] -> bf16[n][k] (zero padded) ----------------
__global__ __launch_bounds__(256)
void tpadT(const float* __restrict__ in, unsigned short* __restrict__ out,
           int ldin, int coff, int Nsrc, int Ksrc, int Kp)
{
  __shared__ float tile[64][65];
  const int kx = threadIdx.x;
  const int ry = threadIdx.y;
  const int k0 = blockIdx.x * 64;
  const int n0 = blockIdx.y * 64;
  for (int r = ry; r < 64; r += 4) {
    const int k = k0 + r;
    const int n = n0 + kx;
    tile[r][kx] = (k < Ksrc && n < Nsrc) ? in[(size_t)k * ldin + coff + n] : 0.f;
  }
  __syncthreads();
  for (int r = ry; r < 64; r += 4) {
    const int n = n0 + r;
    const int k = k0 + kx;
    out[(size_t)n * Kp + k] = f2bf(tile[kx][r]);
  }
}

__global__ __launch_bounds__(256)
void prep_bcat(const float* __restrict__ r_b1, const float* __restrict__ a_b1,
               const float* __restrict__ gh_b1, const float* __restrict__ ex_b1,
               float* __restrict__ bcat)
{
  const int n = blockIdx.x * 256 + threadIdx.x;
  if (n >= 3072) return;
  float v;
  if (n < 256) v = r_b1[n];
  else if (n < 512) v = a_b1[n - 256];
  else if (n < 1024) v = gh_b1[n - 512];
  else v = ex_b1[n - 1024];
  bcat[n] = v;
}

// ---------------- A-matrix for table GEMM: 2304 rows x 1024 bf16 ----------------
// rows 0..100   : tok_w[t] * g
// rows 101..200 : tok_b[t-101] * g   (Q rows for numeric tokens 1..100)
// rows 201..2200: (cat_emb[j] + tok_b[100 + j/100]) * g
// row 2201      : g
// row 2202      : ln_b
// rows 2203+    : 0
__global__ __launch_bounds__(256)
void build_amat(const float* __restrict__ tok_w, const float* __restrict__ tok_b,
                const float* __restrict__ cat_emb,
                const float* __restrict__ ln_g, const float* __restrict__ ln_b,
                unsigned short* __restrict__ Amat)
{
  const int r = blockIdx.x * 4 + (threadIdx.x >> 6);
  const int lane = threadIdx.x & 63;
  if (r >= 2304) return;
  unsigned short* out = Amat + (size_t)r * 1024;
  for (int k = lane * 4; k < 1024; k += 256) {
    floatx4 g = *(const floatx4*)(ln_g + k);
    floatx4 v;
    if (r <= 100) {
      floatx4 a = *(const floatx4*)(tok_w + (size_t)r * 1024 + k);
#pragma unroll
      for (int q = 0; q < 4; q++) v[q] = a[q] * g[q];
    } else if (r <= 200) {
      floatx4 a = *(const floatx4*)(tok_b + (size_t)(r - 101) * 1024 + k);
#pragma unroll
      for (int q = 0; q < 4; q++) v[q] = a[q] * g[q];
    } else if (r <= 2200) {
      const int j = r - 201;
      const int c = j / 100;
      floatx4 a = *(const floatx4*)(cat_emb + (size_t)j * 1024 + k);
      floatx4 bq = *(const floatx4*)(tok_b + (size_t)(100 + c) * 1024 + k);
#pragma unroll
      for (int q = 0; q < 4; q++) v[q] = (a[q] + bq[q]) * g[q];
    } else if (r == 2201) {
      v = g;
    } else if (r == 2202) {
      v = *(const floatx4*)(ln_b + k);
    } else {
      v[0] = 0.f; v[1] = 0.f; v[2] = 0.f; v[3] = 0.f;
    }
    ushortx4 o;
#pragma unroll
    for (int q = 0; q < 4; q++) o[q] = f2bf(v[q]);
    *(ushortx4*)(out + k) = o;
  }
}

// ---------------- per-row scalar sums for closed-form LN stats ----------------
// w 0..100   -> nstat[w][5] = {sum(tok_w), sum(tok_w^2), sum(tok_b), sum(tok_b^2), sum(tok_w*tok_b)}
// w 101..2100-> cstat[j][2] = {sum(row), sum(row^2)}, row = cat_emb[j]+tok_b[100+j/100]
__global__ __launch_bounds__(256)
void stats_rows(const float* __restrict__ tok_w, const float* __restrict__ tok_b,
                const float* __restrict__ cat_emb,
                float* __restrict__ nstat, float* __restrict__ cstat)
{
  const int w = blockIdx.x * 4 + (threadIdx.x >> 6);
  const int lane = threadIdx.x & 63;
  if (w >= 2101) return;
  if (w <= 100) {
    const int t = w;
    const float* wr = tok_w + (size_t)t * 1024;
    const float* br = (t >= 1) ? (tok_b + (size_t)(t - 1) * 1024) : nullptr;
    float sw = 0, sww = 0, sb = 0, sbb = 0, swb = 0;
    for (int k = lane * 4; k < 1024; k += 256) {
      floatx4 a = *(const floatx4*)(wr + k);
#pragma unroll
      for (int q = 0; q < 4; q++) { sw += a[q]; sww += a[q] * a[q]; }
      if (br) {
        floatx4 bq = *(const floatx4*)(br + k);
#pragma unroll
        for (int q = 0; q < 4; q++) { sb += bq[q]; sbb += bq[q] * bq[q]; swb += a[q] * bq[q]; }
      }
    }
    sw = wred(sw); sww = wred(sww); sb = wred(sb); sbb = wred(sbb); swb = wred(swb);
    if (lane == 0) {
      float* ns = nstat + (size_t)t * 5;
      ns[0] = sw; ns[1] = sww; ns[2] = sb; ns[3] = sbb; ns[4] = swb;
    }
  } else {
    const int j = w - 101;
    const int c = j / 100;
    const float* ar = cat_emb + (size_t)j * 1024;
    const float* br = tok_b + (size_t)(100 + c) * 1024;
    float s1 = 0, s2 = 0;
    for (int k = lane * 4; k < 1024; k += 256) {
      floatx4 a = *(const floatx4*)(ar + k);
      floatx4 bq = *(const floatx4*)(br + k);
#pragma unroll
      for (int q = 0; q < 4; q++) { const float v = a[q] + bq[q]; s1 += v; s2 += v * v; }
    }
    s1 = wred(s1); s2 = wred(s2);
    if (lane == 0) { cstat[(size_t)j * 2] = s1; cstat[(size_t)j * 2 + 1] = s2; }
  }
}

// ---------------- generic bf16 GEMM, m97 structure ----------------
// EPI 0: f32 out = acc + bias[n] + extra[n] ; EPI 1: bf16 out = relu(acc+bias) ; EPI 3: f32 out = acc
template<int EPI>
__global__ __launch_bounds__(256)
void gemm_gl(const unsigned short* __restrict__ A, long pitchA,
             const unsigned short* __restrict__ Bw, int K,
             const float* __restrict__ bias, int bias_off,
             const float* __restrict__ extra,
             int NB, int Nvalid, int ldo,
             float* __restrict__ outf, unsigned short* __restrict__ outb)
{
  __shared__ unsigned short As[128 * 32];
  __shared__ unsigned short Bs[128 * 32];
  const int tid = threadIdx.x, lane = tid & 63, wv = tid >> 6;
  const int bid = blockIdx.x;
  const int nb = bid % NB, mb = bid / NB;
  const int m0 = mb * 128, n0 = nb * 128;
  const int wr = (wv >> 1) << 6, wc = (wv & 1) << 6;
  const int fr = lane & 15, fq = lane >> 4;
  const int c0 = wv * 2;
  const int srow = lane >> 2;
  const int sk = (lane & 3) << 3;

  const unsigned short* a0 = A + (size_t)(m0 + c0 * 16 + srow) * pitchA + sk;
  const unsigned short* a1 = A + (size_t)(m0 + (c0 + 1) * 16 + srow) * pitchA + sk;
  const unsigned short* b0p = Bw + (size_t)(n0 + c0 * 16 + srow) * K + sk;
  const unsigned short* b1p = Bw + (size_t)(n0 + (c0 + 1) * 16 + srow) * K + sk;

  f32x4 acc[4][4] = {};
  for (int k0 = 0; k0 < K; k0 += 32) {
    __syncthreads();
    GLOAD16(a0 + k0, &As[c0 * 512]);
    GLOAD16(a1 + k0, &As[(c0 + 1) * 512]);
    GLOAD16(b0p + k0, &Bs[c0 * 512]);
    GLOAD16(b1p + k0, &Bs[(c0 + 1) * 512]);
    __syncthreads();
    bf16x8 af[4], bw_[4];
#pragma unroll
    for (int i = 0; i < 4; i++) {
      af[i]  = *(const bf16x8*)&As[(wr + i * 16 + fr) * 32 + fq * 8];
      bw_[i] = *(const bf16x8*)&Bs[(wc + i * 16 + fr) * 32 + fq * 8];
    }
#pragma unroll
    for (int i = 0; i < 4; i++)
#pragma unroll
      for (int j = 0; j < 4; j++)
        acc[i][j] = __builtin_amdgcn_mfma_f32_16x16x32_bf16(af[i], bw_[j], acc[i][j], 0, 0, 0);
  }

#pragma unroll
  for (int i = 0; i < 4; i++)
#pragma unroll
    for (int j = 0; j < 4; j++) {
      const int n = n0 + wc + j * 16 + fr;
      if (n >= ldo) continue;
      const bool valid = (n < Nvalid);
      const float bv = (EPI == 3) ? 0.f : (valid ? bias[bias_off + n] : 0.f);
      const float ev = (EPI == 0) ? extra[n] : 0.f;
#pragma unroll
      for (int q = 0; q < 4; q++) {
        const int m = m0 + wr + i * 16 + fq * 4 + q;
        const float a = acc[i][j][q];
        if (EPI == 0) {
          outf[(size_t)m * ldo + n] = a + bv + ev;
        } else if (EPI == 1) {
          outb[(size_t)m * ldo + n] = f2bf(fmaxf(a + bv, 0.f));
        } else {
          outf[(size_t)m * ldo + n] = a;
        }
      }
    }
}

// ---------------- constant u vector: gelu(LN(tok_w[0]) @ W_u + b_u) ----------------
__global__ __launch_bounds__(256)
void u_const_k(const unsigned short* __restrict__ w0u, const float* __restrict__ nstat,
               const float* __restrict__ tok_w, const float* __restrict__ ln_g,
               const float* __restrict__ ln_b, const float* __restrict__ lin0_b,
               float* __restrict__ ucon)
{
  __shared__ float xk[1024];
  const int tid = threadIdx.x, lane = tid & 63, wv = tid >> 6;
  const float m = nstat[0] * (1.f / 1024.f);
  const float ex2 = nstat[1] * (1.f / 1024.f);
  const float rs = rsqrtf(ex2 - m * m + 1e-5f);
  for (int k = tid; k < 1024; k += 256)
    xk[k] = bf2f(f2bf((tok_w[k] - m) * rs * ln_g[k] + ln_b[k]));
  __syncthreads();
  const int c = blockIdx.x * 4 + wv;
  if (c >= 704) return;
  if (c >= 675) { if (lane == 0) ucon[c] = 0.f; return; }
  const unsigned short* wr = w0u + (size_t)c * 1024;
  float s = 0.f;
  for (int k = lane; k < 1024; k += 64) s += bf2f(wr[k]) * xk[k];
  s = wred(s);
  if (lane == 0) ucon[c] = gelu_exact(s + lin0_b[c]);
}

// ---------------- the fused v-path: hv rows from tables -> sgu LN stats -> token mix -> u*v ----------------
__global__ __launch_bounds__(512)
void fused_v(const float* __restrict__ TAB, const float* __restrict__ nstat,
             const float* __restrict__ cstat,
             const float* __restrict__ x_num, const int* __restrict__ x_cat,
             const float* __restrict__ sgu_ln_g, const float* __restrict__ sgu_ln_b,
             const float* __restrict__ sgu_w, const float* __restrict__ sgu_b,
             const float* __restrict__ lin0_b, const float* __restrict__ ucon,
             unsigned short* __restrict__ uv)
{
  const int b = blockIdx.x;
  const int tid = threadIdx.x, lane = tid & 63, wv = tid >> 6;
  __shared__ float Rls[704], Cls[704];
  __shared__ float alf[121], bet[121], gam[121];
  __shared__ int   t1r[121], t2r[121];
  __shared__ float wrho[121], muls[121];
  __shared__ float accw[8][704];
  __shared__ float kbs, wss;

  for (int d = tid; d < 704; d += 512) {
    Rls[d] = (d < 675) ? TAB[(size_t)2201 * 768 + d] : 0.f;
    Cls[d] = (d < 675) ? (TAB[(size_t)2202 * 768 + d] + lin0_b[675 + d]) : 0.f;
  }
  if (tid < 121) {
    const int t = tid;
    float m, ex2, sc = 1.f;
    int i1, i2;
    float beflag;
    if (t <= 100) {
      const float* ns = nstat + (size_t)t * 5;
      sc = (t == 0) ? 1.f : x_num[b * 100 + t - 1];
      m = (sc * ns[0] + ns[2]) * (1.f / 1024.f);
      ex2 = (sc * sc * ns[1] + 2.f * sc * ns[4] + ns[3]) * (1.f / 1024.f);
      i1 = t; i2 = (t == 0) ? 2201 : (100 + t);
      beflag = (t == 0) ? 0.f : 1.f;
    } else {
      const int c = t - 101;
      const int j = x_cat[b * 20 + c] + 100 * c;
      m = cstat[(size_t)j * 2] * (1.f / 1024.f);
      ex2 = cstat[(size_t)j * 2 + 1] * (1.f / 1024.f);
      i1 = 201 + j; i2 = 2201; beflag = 0.f;
    }
    const float var = ex2 - m * m;
    const float rs = rsqrtf(var + 1e-5f);
    alf[t] = rs * sc;
    bet[t] = beflag * rs;
    gam[t] = -m * rs;
    t1r[t] = i1; t2r[t] = i2;
  }
  __syncthreads();

  // pass 1: compute hv vals (one gelu pass), keep packed bf16 in registers, wave-reduce sgu-LN stats
  unsigned int p[16][6];
#pragma unroll
  for (int i = 0; i < 16; i++) {
    const int t = wv + 8 * i;
    const bool tv = (t < 121);
    float a = 0.f, be = 0.f, ga = 0.f;
    const float* T1 = TAB;
    const float* T2 = TAB;
    if (tv) {
      a = alf[t]; be = bet[t]; ga = gam[t];
      T1 = TAB + (size_t)t1r[t] * 768;
      T2 = TAB + (size_t)t2r[t] * 768;
    }
    float s = 0.f, ss = 0.f;
#pragma unroll
    for (int j = 0; j < 11; j++) {
      const int d = lane + 64 * j;
      float val = 0.f;
      if (tv && d < 675) {
        const float pre = a * T1[d] + be * T2[d] + ga * Rls[d] + Cls[d];
        val = gelu_exact(pre);
        s += val; ss += val * val;
      }
      const unsigned int pk = (unsigned int)f2bf(val);
      if ((j & 1) == 0) p[i][j >> 1] = pk;
      else p[i][j >> 1] |= (pk << 16);
    }
    s = wred(s); ss = wred(ss);
    if (tv && lane == 0) {
      const float mu = s * (1.f / 675.f);
      const float var = ss * (1.f / 675.f) - mu * mu;
      const float rho = rsqrtf(var + 1e-5f);
      muls[t] = mu;
      wrho[t] = sgu_w[t] * rho;
    }
  }
  __syncthreads();
  if (wv == 0) {
    float kb = 0.f, ws = 0.f;
    for (int t = lane; t < 121; t += 64) { kb += wrho[t] * muls[t]; ws += sgu_w[t]; }
    kb = wred(kb); ws = wred(ws);
    if (lane == 0) { kbs = kb; wss = ws; }
  }

  // pass 2: per-wave weighted accumulation of cached vals
  float acc[11];
#pragma unroll
  for (int j = 0; j < 11; j++) acc[j] = 0.f;
#pragma unroll
  for (int i = 0; i < 16; i++) {
    const int t = wv + 8 * i;
    if (t < 121) {
      const float wr = wrho[t];
#pragma unroll
      for (int j = 0; j < 11; j++) {
        const unsigned int pk = p[i][j >> 1];
        const unsigned short h = ((j & 1) == 0) ? (unsigned short)(pk & 0xffffu)
                                                : (unsigned short)(pk >> 16);
        acc[j] += wr * bf2f(h);
      }
    }
  }
#pragma unroll
  for (int j = 0; j < 11; j++) accw[wv][lane + 64 * j] = acc[j];
  __syncthreads();

  const float sb0 = sgu_b[0];
  for (int d = tid; d < 704; d += 512) {
    unsigned short o = 0;
    if (d < 675) {
      float a = 0.f;
#pragma unroll
      for (int w = 0; w < 8; w++) a += accw[w][d];
      const float v0 = sgu_ln_g[d] * (a - kbs) + sgu_ln_b[d] * wss + sb0;
      o = f2bf(ucon[d] * v0);
    }
    uv[(size_t)b * 704 + d] = o;
  }
}

// ---------------- LN + gelu -> hidden (f32 + bf16) ----------------
__global__ __launch_bounds__(256)
void ln_gelu_hidden(const float* __restrict__ xfin,
                    const float* __restrict__ ln_g, const float* __restrict__ ln_b,
                    float* __restrict__ hid_f, unsigned short* __restrict__ hid_bf)
{
  const int w = (blockIdx.x * 256 + threadIdx.x) >> 6;
  const int lane = threadIdx.x & 63;
  if (w >= B_SZ) return;
  const float* row = xfin + (size_t)w * 1024;
  float s = 0.f, ss = 0.f;
  for (int k = lane; k < 1024; k += 64) { float v = row[k]; s += v; ss += v * v; }
  s = wred(s); ss = wred(ss);
  const float m = s * (1.f / 1024.f);
  const float var = ss * (1.f / 1024.f) - m * m;
  const float rs = rsqrtf(var + 1e-5f);
  for (int k = lane; k < 1024; k += 64) {
    float v = gelu_exact((row[k] - m) * rs * ln_g[k] + ln_b[k]);
    hid_f[(size_t)w * 1024 + k] = v;
    hid_bf[(size_t)w * 1024 + k] = f2bf(v);
  }
}

// ---------------- per-row finale ----------------
__global__ __launch_bounds__(256)
void final_head(const unsigned short* __restrict__ H1, const float* __restrict__ hid_f,
                const float* __restrict__ r_w2, const float* __restrict__ r_b2,
                const float* __restrict__ a_w2, const float* __restrict__ a_b2,
                const float* __restrict__ gh_w2, const float* __restrict__ gh_b2,
                const float* __restrict__ ex_w2, const float* __restrict__ ex_b2,
                const float* __restrict__ base_w, const float* __restrict__ base_b,
                float* __restrict__ out)
{
  const int b = blockIdx.x;
  const int tid = threadIdx.x;
  const unsigned short* h1 = H1 + (size_t)b * 3072;
  float p[11];
#pragma unroll
  for (int i = 0; i < 11; i++) p[i] = 0.f;
  {
    const int m = tid;
    const float hr = bf2f(h1[m]);
    p[0] = hr * r_w2[m * 4 + 0];
    p[1] = hr * r_w2[m * 4 + 1];
    p[2] = hr * r_w2[m * 4 + 2];
    p[3] = hr * r_w2[m * 4 + 3];
    const float ha = bf2f(h1[256 + m]);
    p[4] = ha * a_w2[m];
  }
  for (int m = tid; m < 512; m += 256) {
    p[5] += bf2f(h1[512 + m]) * gh_w2[m];
#pragma unroll
    for (int e = 0; e < 4; e++)
      p[6 + e] += bf2f(h1[1024 + e * 512 + m]) * ex_w2[e * 512 + m];
  }
  for (int k = tid; k < 1024; k += 256) p[10] += hid_f[(size_t)b * 1024 + k] * base_w[k];

  __shared__ float red[11][4];
  const int lane = tid & 63, wv = tid >> 6;
#pragma unroll
  for (int i = 0; i < 11; i++) {
    const float v = wred(p[i]);
    if (lane == 0) red[i][wv] = v;
  }
  __syncthreads();
  if (tid == 0) {
    float s[11];
#pragma unroll
    for (int i = 0; i < 11; i++) s[i] = red[i][0] + red[i][1] + red[i][2] + red[i][3];
    float lg[4];
#pragma unroll
    for (int e = 0; e < 4; e++) lg[e] = s[e] + r_b2[e];
    const float mx = fmaxf(fmaxf(lg[0], lg[1]), fmaxf(lg[2], lg[3]));
    float den[4]; float dsum = 0.f;
#pragma unroll
    for (int e = 0; e < 4; e++) { den[e] = expf(lg[e] - mx); dsum += den[e]; }
#pragma unroll
    for (int e = 0; e < 4; e++) den[e] /= dsum;
    int i1 = 0;
    for (int e = 1; e < 4; e++) if (den[e] > den[i1]) i1 = e;
    int i2 = -1;
    for (int e = 0; e < 4; e++) { if (e == i1) continue; if (i2 < 0 || den[e] > den[i2]) i2 = e; }
    float eo[4];
#pragma unroll
    for (int e = 0; e < 4; e++) eo[e] = s[6 + e] + ex_b2[e];
    const float v1 = den[i1], v2 = den[i2];
    const float ssum = fmaxf(v1 + v2, 1e-8f);
    const float local = (v1 * eo[i1] + v2 * eo[i2]) / ssum;
    const float glob = s[5] + gh_b2[0];
    const float alpha = 1.0f / (1.0f + expf(-(s[4] + a_b2[0])));
    out[b] = s[10] + base_b[0] + alpha * (glob + local);
  }
}

extern "C" void kernel_launch(void* const* d_in, const int* in_sizes, int n_in,
                              void* d_out, int out_size, void* d_ws, size_t ws_size,
                              hipStream_t stream)
{
  const float* x_num  = (const float*)d_in[0];
  const int*   x_cat  = (const int*)d_in[1];
  const float* tok_w  = (const float*)d_in[2];
  const float* tok_b  = (const float*)d_in[3];
  const float* cat_emb= (const float*)d_in[4];
  const float* ln_g   = (const float*)d_in[5];
  const float* ln_b   = (const float*)d_in[6];
  const float* lin0_w = (const float*)d_in[7];
  const float* lin0_b = (const float*)d_in[8];
  const float* sgu_ln_g = (const float*)d_in[9];
  const float* sgu_ln_b = (const float*)d_in[10];
  const float* sgu_w  = (const float*)d_in[11];
  const float* sgu_b  = (const float*)d_in[12];
  const float* lin1_w = (const float*)d_in[13];
  const float* lin1_b = (const float*)d_in[14];
  const float* r_w1   = (const float*)d_in[15];
  const float* r_b1   = (const float*)d_in[16];
  const float* r_w2   = (const float*)d_in[17];
  const float* r_b2   = (const float*)d_in[18];
  const float* a_w1   = (const float*)d_in[19];
  const float* a_b1   = (const float*)d_in[20];
  const float* a_w2   = (const float*)d_in[21];
  const float* a_b2   = (const float*)d_in[22];
  const float* base_w = (const float*)d_in[23];
  const float* base_b = (const float*)d_in[24];
  const float* gh_w1  = (const float*)d_in[25];
  const float* gh_b1  = (const float*)d_in[26];
  const float* gh_w2  = (const float*)d_in[27];
  const float* gh_b2  = (const float*)d_in[28];
  const float* ex_w1  = (const float*)d_in[29];
  const float* ex_b1  = (const float*)d_in[30];
  const float* ex_w2  = (const float*)d_in[31];
  const float* ex_b2  = (const float*)d_in[32];
  (void)in_sizes; (void)n_in; (void)out_size; (void)ws_size;

  char* ws = (char*)d_ws;
  size_t off = 0;
  auto alloc = [&](size_t bytes) { void* p = ws + off; off += (bytes + 255) & ~(size_t)255; return p; };

  unsigned short* w0v  = (unsigned short*)alloc((size_t)768 * 1024 * 2);
  unsigned short* w0u  = (unsigned short*)alloc((size_t)768 * 1024 * 2);
  unsigned short* w1t  = (unsigned short*)alloc((size_t)1024 * 704 * 2);
  unsigned short* wcat = (unsigned short*)alloc((size_t)3072 * 1024 * 2);
  float* bcat          = (float*)alloc((size_t)3072 * 4);
  unsigned short* Amat = (unsigned short*)alloc((size_t)2304 * 1024 * 2);
  float* TAB           = (float*)alloc((size_t)2304 * 768 * 4);
  float* nstat         = (float*)alloc((size_t)101 * 5 * 4);
  float* cstat         = (float*)alloc((size_t)2000 * 2 * 4);
  float* ucon          = (float*)alloc((size_t)704 * 4);
  unsigned short* uv   = (unsigned short*)alloc((size_t)B_SZ * 704 * 2);
  float* xfin          = (float*)alloc((size_t)B_SZ * 1024 * 4);
  float* hid_f         = (float*)alloc((size_t)B_SZ * 1024 * 4);
  unsigned short* hidb = (unsigned short*)alloc((size_t)B_SZ * 1024 * 2);
  unsigned short* H1   = (unsigned short*)alloc((size_t)B_SZ * 3072 * 2);

  const dim3 blk(256);
  const dim3 tblk(64, 4);

  // weight prep
  tpadT<<<dim3(16, 12), tblk, 0, stream>>>(lin0_w, w0v, 1350, 675, 675, 1024, 1024);
  tpadT<<<dim3(16, 12), tblk, 0, stream>>>(lin0_w, w0u, 1350, 0, 675, 1024, 1024);
  tpadT<<<dim3(11, 16), tblk, 0, stream>>>(lin1_w, w1t, 1024, 0, 1024, 675, 704);
  tpadT<<<dim3(16, 4), tblk, 0, stream>>>(r_w1, wcat, 256, 0, 256, 1024, 1024);
  tpadT<<<dim3(16, 4), tblk, 0, stream>>>(a_w1, wcat + (size_t)256 * 1024, 256, 0, 256, 1024, 1024);
  tpadT<<<dim3(16, 8), tblk, 0, stream>>>(gh_w1, wcat + (size_t)512 * 1024, 512, 0, 512, 1024, 1024);
  for (int e = 0; e < 4; e++)
    tpadT<<<dim3(16, 8), tblk, 0, stream>>>(ex_w1 + (size_t)e * 1024 * 512,
        wcat + (size_t)(1024 + e * 512) * 1024, 512, 0, 512, 1024, 1024);
  prep_bcat<<<12, blk, 0, stream>>>(r_b1, a_b1, gh_b1, ex_b1, bcat);

  // tables + stats
  build_amat<<<576, blk, 0, stream>>>(tok_w, tok_b, cat_emb, ln_g, ln_b, Amat);
  stats_rows<<<526, blk, 0, stream>>>(tok_w, tok_b, cat_emb, nstat, cstat);
  gemm_gl<3><<<18 * 6, blk, 0, stream>>>(Amat, 1024, w0v, 1024,
      nullptr, 0, nullptr, 6, 768, 768, TAB, nullptr);

  // constant u + fused v path -> uv
  u_const_k<<<176, blk, 0, stream>>>(w0u, nstat, tok_w, ln_g, ln_b, lin0_b, ucon);
  fused_v<<<B_SZ, dim3(512), 0, stream>>>(TAB, nstat, cstat, x_num, x_cat,
      sgu_ln_g, sgu_ln_b, sgu_w, sgu_b, lin0_b, ucon, uv);

  // tail
  gemm_gl<0><<<8 * 8, blk, 0, stream>>>(uv, 704, w1t, 704,
      lin1_b, 0, tok_w, 8, 1024, 1024, xfin, nullptr);
  ln_gelu_hidden<<<B_SZ / 4, blk, 0, stream>>>(xfin, ln_g, ln_b, hid_f, hidb);
  gemm_gl<1><<<8 * 24, blk, 0, stream>>>(hidb, 1024, wcat, 1024,
      bcat, 0, nullptr, 24, 3072, 3072, nullptr, H1);

  final_head<<<B_SZ, blk, 0, stream>>>(H1, hid_f, r_w2, r_b2, a_w2, a_b2, gh_w2, gh_b2,
                                       ex_w2, ex_b2, base_w, base_b, (float*)d_out);
}

// Round 4
// 312.537 us; speedup vs baseline: 4.0088x; 2.4302x over previous
//
#include <hip/hip_runtime.h>
#include <math.h>

#define B_SZ 1024

typedef __attribute__((ext_vector_type(8))) short bf16x8;
typedef __attribute__((ext_vector_type(4))) float f32x4;
typedef __attribute__((ext_vector_type(4))) float floatx4;
typedef __attribute__((ext_vector_type(4))) unsigned short ushortx4;

#define GLOAD16(src, dst) __builtin_amdgcn_global_load_lds( \
    (const __attribute__((address_space(1))) void*)(src), \
    (__attribute__((address_space(3))) void*)(dst), 16, 0, 0)

__device__ __forceinline__ unsigned short f2bf(float f) {
  unsigned int u = __float_as_uint(f);
  u += 0x7fff + ((u >> 16) & 1);
  return (unsigned short)(u >> 16);
}
__device__ __forceinline__ float bf2f(unsigned short b) {
  return __uint_as_float(((unsigned int)b) << 16);
}
__device__ __forceinline__ float gelu_exact(float x) {
  return 0.5f * x * (1.0f + erff(x * 0.70710678118654752f));
}
__device__ __forceinline__ float wred(float v) {
#pragma unroll
  for (int o = 32; o > 0; o >>= 1) v += __shfl_xor(v, o, 64);
  return v;
}

// ---------------- tiled transpose f32[k][n] -> bf16[n][k] (zero padded) ----------------
__global__ __launch_bounds__(256)
void tpadT(const float* __restrict__ in, unsigned short* __restrict__ out,
           int ldin, int coff, int Nsrc, int Ksrc, int Kp)
{
  __shared__ float tile[64][65];
  const int kx = threadIdx.x;
  const int ry = threadIdx.y;
  const int k0 = blockIdx.x * 64;
  const int n0 = blockIdx.y * 64;
  for (int r = ry; r < 64; r += 4) {
    const int k = k0 + r;
    const int n = n0 + kx;
    tile[r][kx] = (k < Ksrc && n < Nsrc) ? in[(size_t)k * ldin + coff + n] : 0.f;
  }
  __syncthreads();
  for (int r = ry; r < 64; r += 4) {
    const int n = n0 + r;
    const int k = k0 + kx;
    out[(size_t)n * Kp + k] = f2bf(tile[kx][r]);
  }
}

__global__ __launch_bounds__(256)
void prep_bcat(const float* __restrict__ r_b1, const float* __restrict__ a_b1,
               const float* __restrict__ gh_b1, const float* __restrict__ ex_b1,
               float* __restrict__ bcat)
{
  const int n = blockIdx.x * 256 + threadIdx.x;
  if (n >= 3072) return;
  float v;
  if (n < 256) v = r_b1[n];
  else if (n < 512) v = a_b1[n - 256];
  else if (n < 1024) v = gh_b1[n - 512];
  else v = ex_b1[n - 1024];
  bcat[n] = v;
}

// ---------------- A-matrix for table GEMM: 2304 rows x 1024 bf16 ----------------
__global__ __launch_bounds__(256)
void build_amat(const float* __restrict__ tok_w, const float* __restrict__ tok_b,
                const float* __restrict__ cat_emb,
                const float* __restrict__ ln_g, const float* __restrict__ ln_b,
                unsigned short* __restrict__ Amat)
{
  const int r = blockIdx.x * 4 + (threadIdx.x >> 6);
  const int lane = threadIdx.x & 63;
  if (r >= 2304) return;
  unsigned short* out = Amat + (size_t)r * 1024;
  for (int k = lane * 4; k < 1024; k += 256) {
    floatx4 g = *(const floatx4*)(ln_g + k);
    floatx4 v;
    if (r <= 100) {
      floatx4 a = *(const floatx4*)(tok_w + (size_t)r * 1024 + k);
#pragma unroll
      for (int q = 0; q < 4; q++) v[q] = a[q] * g[q];
    } else if (r <= 200) {
      floatx4 a = *(const floatx4*)(tok_b + (size_t)(r - 101) * 1024 + k);
#pragma unroll
      for (int q = 0; q < 4; q++) v[q] = a[q] * g[q];
    } else if (r <= 2200) {
      const int j = r - 201;
      const int c = j / 100;
      floatx4 a = *(const floatx4*)(cat_emb + (size_t)j * 1024 + k);
      floatx4 bq = *(const floatx4*)(tok_b + (size_t)(100 + c) * 1024 + k);
#pragma unroll
      for (int q = 0; q < 4; q++) v[q] = (a[q] + bq[q]) * g[q];
    } else if (r == 2201) {
      v = g;
    } else if (r == 2202) {
      v = *(const floatx4*)(ln_b + k);
    } else {
      v[0] = 0.f; v[1] = 0.f; v[2] = 0.f; v[3] = 0.f;
    }
    ushortx4 o;
#pragma unroll
    for (int q = 0; q < 4; q++) o[q] = f2bf(v[q]);
    *(ushortx4*)(out + k) = o;
  }
}

// ---------------- per-row scalar sums for closed-form LN stats ----------------
__global__ __launch_bounds__(256)
void stats_rows(const float* __restrict__ tok_w, const float* __restrict__ tok_b,
                const float* __restrict__ cat_emb,
                float* __restrict__ nstat, float* __restrict__ cstat)
{
  const int w = blockIdx.x * 4 + (threadIdx.x >> 6);
  const int lane = threadIdx.x & 63;
  if (w >= 2101) return;
  if (w <= 100) {
    const int t = w;
    const float* wr = tok_w + (size_t)t * 1024;
    const float* br = (t >= 1) ? (tok_b + (size_t)(t - 1) * 1024) : nullptr;
    float sw = 0, sww = 0, sb = 0, sbb = 0, swb = 0;
    for (int k = lane * 4; k < 1024; k += 256) {
      floatx4 a = *(const floatx4*)(wr + k);
#pragma unroll
      for (int q = 0; q < 4; q++) { sw += a[q]; sww += a[q] * a[q]; }
      if (br) {
        floatx4 bq = *(const floatx4*)(br + k);
#pragma unroll
        for (int q = 0; q < 4; q++) { sb += bq[q]; sbb += bq[q] * bq[q]; swb += a[q] * bq[q]; }
      }
    }
    sw = wred(sw); sww = wred(sww); sb = wred(sb); sbb = wred(sbb); swb = wred(swb);
    if (lane == 0) {
      float* ns = nstat + (size_t)t * 5;
      ns[0] = sw; ns[1] = sww; ns[2] = sb; ns[3] = sbb; ns[4] = swb;
    }
  } else {
    const int j = w - 101;
    const int c = j / 100;
    const float* ar = cat_emb + (size_t)j * 1024;
    const float* br = tok_b + (size_t)(100 + c) * 1024;
    float s1 = 0, s2 = 0;
    for (int k = lane * 4; k < 1024; k += 256) {
      floatx4 a = *(const floatx4*)(ar + k);
      floatx4 bq = *(const floatx4*)(br + k);
#pragma unroll
      for (int q = 0; q < 4; q++) { const float v = a[q] + bq[q]; s1 += v; s2 += v * v; }
    }
    s1 = wred(s1); s2 = wred(s2);
    if (lane == 0) { cstat[(size_t)j * 2] = s1; cstat[(size_t)j * 2 + 1] = s2; }
  }
}

// ---------------- generic bf16 GEMM, m97 structure ----------------
template<int EPI>
__global__ __launch_bounds__(256)
void gemm_gl(const unsigned short* __restrict__ A, long pitchA,
             const unsigned short* __restrict__ Bw, int K,
             const float* __restrict__ bias, int bias_off,
             const float* __restrict__ extra,
             int NB, int Nvalid, int ldo,
             float* __restrict__ outf, unsigned short* __restrict__ outb)
{
  __shared__ unsigned short As[128 * 32];
  __shared__ unsigned short Bs[128 * 32];
  const int tid = threadIdx.x, lane = tid & 63, wv = tid >> 6;
  const int bid = blockIdx.x;
  const int nb = bid % NB, mb = bid / NB;
  const int m0 = mb * 128, n0 = nb * 128;
  const int wr = (wv >> 1) << 6, wc = (wv & 1) << 6;
  const int fr = lane & 15, fq = lane >> 4;
  const int c0 = wv * 2;
  const int srow = lane >> 2;
  const int sk = (lane & 3) << 3;

  const unsigned short* a0 = A + (size_t)(m0 + c0 * 16 + srow) * pitchA + sk;
  const unsigned short* a1 = A + (size_t)(m0 + (c0 + 1) * 16 + srow) * pitchA + sk;
  const unsigned short* b0p = Bw + (size_t)(n0 + c0 * 16 + srow) * K + sk;
  const unsigned short* b1p = Bw + (size_t)(n0 + (c0 + 1) * 16 + srow) * K + sk;

  f32x4 acc[4][4] = {};
  for (int k0 = 0; k0 < K; k0 += 32) {
    __syncthreads();
    GLOAD16(a0 + k0, &As[c0 * 512]);
    GLOAD16(a1 + k0, &As[(c0 + 1) * 512]);
    GLOAD16(b0p + k0, &Bs[c0 * 512]);
    GLOAD16(b1p + k0, &Bs[(c0 + 1) * 512]);
    __syncthreads();
    bf16x8 af[4], bw_[4];
#pragma unroll
    for (int i = 0; i < 4; i++) {
      af[i]  = *(const bf16x8*)&As[(wr + i * 16 + fr) * 32 + fq * 8];
      bw_[i] = *(const bf16x8*)&Bs[(wc + i * 16 + fr) * 32 + fq * 8];
    }
#pragma unroll
    for (int i = 0; i < 4; i++)
#pragma unroll
      for (int j = 0; j < 4; j++)
        acc[i][j] = __builtin_amdgcn_mfma_f32_16x16x32_bf16(af[i], bw_[j], acc[i][j], 0, 0, 0);
  }

#pragma unroll
  for (int i = 0; i < 4; i++)
#pragma unroll
    for (int j = 0; j < 4; j++) {
      const int n = n0 + wc + j * 16 + fr;
      if (n >= ldo) continue;
      const bool valid = (n < Nvalid);
      const float bv = (EPI == 3) ? 0.f : (valid ? bias[bias_off + n] : 0.f);
      const float ev = (EPI == 0) ? extra[n] : 0.f;
#pragma unroll
      for (int q = 0; q < 4; q++) {
        const int m = m0 + wr + i * 16 + fq * 4 + q;
        const float a = acc[i][j][q];
        if (EPI == 0) {
          outf[(size_t)m * ldo + n] = a + bv + ev;
        } else if (EPI == 1) {
          outb[(size_t)m * ldo + n] = f2bf(fmaxf(a + bv, 0.f));
        } else {
          outf[(size_t)m * ldo + n] = a;
        }
      }
    }
}

// ---------------- constant u vector: gelu(LN(tok_w[0]) @ W_u + b_u) ----------------
__global__ __launch_bounds__(256)
void u_const_k(const unsigned short* __restrict__ w0u, const float* __restrict__ nstat,
               const float* __restrict__ tok_w, const float* __restrict__ ln_g,
               const float* __restrict__ ln_b, const float* __restrict__ lin0_b,
               float* __restrict__ ucon)
{
  __shared__ float xk[1024];
  const int tid = threadIdx.x, lane = tid & 63, wv = tid >> 6;
  const float m = nstat[0] * (1.f / 1024.f);
  const float ex2 = nstat[1] * (1.f / 1024.f);
  const float rs = rsqrtf(ex2 - m * m + 1e-5f);
  for (int k = tid; k < 1024; k += 256)
    xk[k] = bf2f(f2bf((tok_w[k] - m) * rs * ln_g[k] + ln_b[k]));
  __syncthreads();
  const int c = blockIdx.x * 4 + wv;
  if (c >= 704) return;
  if (c >= 675) { if (lane == 0) ucon[c] = 0.f; return; }
  const unsigned short* wr = w0u + (size_t)c * 1024;
  float s = 0.f;
  for (int k = lane; k < 1024; k += 64) s += bf2f(wr[k]) * xk[k];
  s = wred(s);
  if (lane == 0) ucon[c] = gelu_exact(s + lin0_b[c]);
}

// ---------------- fused v-path: single-pass stats+accumulate (no register cache, no spill) ----------------
__global__ __launch_bounds__(512)
void fused_v(const float* __restrict__ TAB, const float* __restrict__ nstat,
             const float* __restrict__ cstat,
             const float* __restrict__ x_num, const int* __restrict__ x_cat,
             const float* __restrict__ sgu_ln_g, const float* __restrict__ sgu_ln_b,
             const float* __restrict__ sgu_w, const float* __restrict__ sgu_b,
             const float* __restrict__ lin0_b, const float* __restrict__ ucon,
             unsigned short* __restrict__ uv)
{
  const int b = blockIdx.x;
  const int tid = threadIdx.x, lane = tid & 63, wv = tid >> 6;
  __shared__ float Rls[704], Cls[704];
  __shared__ float alf[121], bet[121], gam[121], swt_s[121];
  __shared__ int   t1r[121], t2r[121];
  __shared__ float accw[8][704];
  __shared__ float kbw[8], wsw[8];

  for (int d = tid; d < 704; d += 512) {
    Rls[d] = (d < 675) ? TAB[(size_t)2201 * 768 + d] : 0.f;
    Cls[d] = (d < 675) ? (TAB[(size_t)2202 * 768 + d] + lin0_b[675 + d]) : 0.f;
  }
  if (tid < 121) {
    const int t = tid;
    float m, ex2, sc = 1.f;
    int i1, i2;
    float beflag;
    if (t <= 100) {
      const float* ns = nstat + (size_t)t * 5;
      sc = (t == 0) ? 1.f : x_num[b * 100 + t - 1];
      m = (sc * ns[0] + ns[2]) * (1.f / 1024.f);
      ex2 = (sc * sc * ns[1] + 2.f * sc * ns[4] + ns[3]) * (1.f / 1024.f);
      i1 = t; i2 = (t == 0) ? 2201 : (100 + t);
      beflag = (t == 0) ? 0.f : 1.f;
    } else {
      const int c = t - 101;
      const int j = x_cat[b * 20 + c] + 100 * c;
      m = cstat[(size_t)j * 2] * (1.f / 1024.f);
      ex2 = cstat[(size_t)j * 2 + 1] * (1.f / 1024.f);
      i1 = 201 + j; i2 = 2201; beflag = 0.f;
    }
    const float var = ex2 - m * m;
    const float rs = rsqrtf(var + 1e-5f);
    alf[t] = rs * sc;
    bet[t] = beflag * rs;
    gam[t] = -m * rs;
    t1r[t] = i1; t2r[t] = i2;
    swt_s[t] = sgu_w[t];
  }
  __syncthreads();

  // single pass: per token -> vals in regs -> wave-reduce stats -> immediately accumulate
  float acc[11];
#pragma unroll
  for (int j = 0; j < 11; j++) acc[j] = 0.f;
  float kb = 0.f, wsum = 0.f;

  for (int i = 0; i < 16; i++) {
    const int t = wv + 8 * i;
    if (t >= 121) break;
    const float a = alf[t], be = bet[t], ga = gam[t];
    const float* T1 = TAB + (size_t)t1r[t] * 768;
    const float* T2 = TAB + (size_t)t2r[t] * 768;
    float val[11];
    float s = 0.f, ss = 0.f;
#pragma unroll
    for (int j = 0; j < 11; j++) {
      const int d = lane + 64 * j;
      float v = 0.f;
      if (d < 675) {
        v = gelu_exact(a * T1[d] + be * T2[d] + ga * Rls[d] + Cls[d]);
        s += v; ss += v * v;
      }
      val[j] = v;
    }
    s = wred(s); ss = wred(ss);   // butterfly: every lane holds the full sum
    const float mu = s * (1.f / 675.f);
    const float rho = rsqrtf(ss * (1.f / 675.f) - mu * mu + 1e-5f);
    const float sw = swt_s[t];
    const float wr = sw * rho;
#pragma unroll
    for (int j = 0; j < 11; j++) acc[j] += wr * val[j];
    kb += wr * mu;
    wsum += sw;
  }

#pragma unroll
  for (int j = 0; j < 11; j++) accw[wv][lane + 64 * j] = acc[j];
  if (lane == 0) { kbw[wv] = kb; wsw[wv] = wsum; }
  __syncthreads();

  float kbs = 0.f, wss = 0.f;
#pragma unroll
  for (int w = 0; w < 8; w++) { kbs += kbw[w]; wss += wsw[w]; }
  const float sb0 = sgu_b[0];
  for (int d = tid; d < 704; d += 512) {
    unsigned short o = 0;
    if (d < 675) {
      float a = 0.f;
#pragma unroll
      for (int w = 0; w < 8; w++) a += accw[w][d];
      const float v0 = sgu_ln_g[d] * (a - kbs) + sgu_ln_b[d] * wss + sb0;
      o = f2bf(ucon[d] * v0);
    }
    uv[(size_t)b * 704 + d] = o;
  }
}

// ---------------- LN + gelu -> hidden (f32 + bf16) ----------------
__global__ __launch_bounds__(256)
void ln_gelu_hidden(const float* __restrict__ xfin,
                    const float* __restrict__ ln_g, const float* __restrict__ ln_b,
                    float* __restrict__ hid_f, unsigned short* __restrict__ hid_bf)
{
  const int w = (blockIdx.x * 256 + threadIdx.x) >> 6;
  const int lane = threadIdx.x & 63;
  if (w >= B_SZ) return;
  const float* row = xfin + (size_t)w * 1024;
  float s = 0.f, ss = 0.f;
  for (int k = lane; k < 1024; k += 64) { float v = row[k]; s += v; ss += v * v; }
  s = wred(s); ss = wred(ss);
  const float m = s * (1.f / 1024.f);
  const float var = ss * (1.f / 1024.f) - m * m;
  const float rs = rsqrtf(var + 1e-5f);
  for (int k = lane; k < 1024; k += 64) {
    float v = gelu_exact((row[k] - m) * rs * ln_g[k] + ln_b[k]);
    hid_f[(size_t)w * 1024 + k] = v;
    hid_bf[(size_t)w * 1024 + k] = f2bf(v);
  }
}

// ---------------- per-row finale ----------------
__global__ __launch_bounds__(256)
void final_head(const unsigned short* __restrict__ H1, const float* __restrict__ hid_f,
                const float* __restrict__ r_w2, const float* __restrict__ r_b2,
                const float* __restrict__ a_w2, const float* __restrict__ a_b2,
                const float* __restrict__ gh_w2, const float* __restrict__ gh_b2,
                const float* __restrict__ ex_w2, const float* __restrict__ ex_b2,
                const float* __restrict__ base_w, const float* __restrict__ base_b,
                float* __restrict__ out)
{
  const int b = blockIdx.x;
  const int tid = threadIdx.x;
  const unsigned short* h1 = H1 + (size_t)b * 3072;
  float p[11];
#pragma unroll
  for (int i = 0; i < 11; i++) p[i] = 0.f;
  {
    const int m = tid;
    const float hr = bf2f(h1[m]);
    p[0] = hr * r_w2[m * 4 + 0];
    p[1] = hr * r_w2[m * 4 + 1];
    p[2] = hr * r_w2[m * 4 + 2];
    p[3] = hr * r_w2[m * 4 + 3];
    const float ha = bf2f(h1[256 + m]);
    p[4] = ha * a_w2[m];
  }
  for (int m = tid; m < 512; m += 256) {
    p[5] += bf2f(h1[512 + m]) * gh_w2[m];
#pragma unroll
    for (int e = 0; e < 4; e++)
      p[6 + e] += bf2f(h1[1024 + e * 512 + m]) * ex_w2[e * 512 + m];
  }
  for (int k = tid; k < 1024; k += 256) p[10] += hid_f[(size_t)b * 1024 + k] * base_w[k];

  __shared__ float red[11][4];
  const int lane = tid & 63, wv = tid >> 6;
#pragma unroll
  for (int i = 0; i < 11; i++) {
    const float v = wred(p[i]);
    if (lane == 0) red[i][wv] = v;
  }
  __syncthreads();
  if (tid == 0) {
    float s[11];
#pragma unroll
    for (int i = 0; i < 11; i++) s[i] = red[i][0] + red[i][1] + red[i][2] + red[i][3];
    float lg[4];
#pragma unroll
    for (int e = 0; e < 4; e++) lg[e] = s[e] + r_b2[e];
    const float mx = fmaxf(fmaxf(lg[0], lg[1]), fmaxf(lg[2], lg[3]));
    float den[4]; float dsum = 0.f;
#pragma unroll
    for (int e = 0; e < 4; e++) { den[e] = expf(lg[e] - mx); dsum += den[e]; }
#pragma unroll
    for (int e = 0; e < 4; e++) den[e] /= dsum;
    int i1 = 0;
    for (int e = 1; e < 4; e++) if (den[e] > den[i1]) i1 = e;
    int i2 = -1;
    for (int e = 0; e < 4; e++) { if (e == i1) continue; if (i2 < 0 || den[e] > den[i2]) i2 = e; }
    float eo[4];
#pragma unroll
    for (int e = 0; e < 4; e++) eo[e] = s[6 + e] + ex_b2[e];
    const float v1 = den[i1], v2 = den[i2];
    const float ssum = fmaxf(v1 + v2, 1e-8f);
    const float local = (v1 * eo[i1] + v2 * eo[i2]) / ssum;
    const float glob = s[5] + gh_b2[0];
    const float alpha = 1.0f / (1.0f + expf(-(s[4] + a_b2[0])));
    out[b] = s[10] + base_b[0] + alpha * (glob + local);
  }
}

extern "C" void kernel_launch(void* const* d_in, const int* in_sizes, int n_in,
                              void* d_out, int out_size, void* d_ws, size_t ws_size,
                              hipStream_t stream)
{
  const float* x_num  = (const float*)d_in[0];
  const int*   x_cat  = (const int*)d_in[1];
  const float* tok_w  = (const float*)d_in[2];
  const float* tok_b  = (const float*)d_in[3];
  const float* cat_emb= (const float*)d_in[4];
  const float* ln_g   = (const float*)d_in[5];
  const float* ln_b   = (const float*)d_in[6];
  const float* lin0_w = (const float*)d_in[7];
  const float* lin0_b = (const float*)d_in[8];
  const float* sgu_ln_g = (const float*)d_in[9];
  const float* sgu_ln_b = (const float*)d_in[10];
  const float* sgu_w  = (const float*)d_in[11];
  const float* sgu_b  = (const float*)d_in[12];
  const float* lin1_w = (const float*)d_in[13];
  const float* lin1_b = (const float*)d_in[14];
  const float* r_w1   = (const float*)d_in[15];
  const float* r_b1   = (const float*)d_in[16];
  const float* r_w2   = (const float*)d_in[17];
  const float* r_b2   = (const float*)d_in[18];
  const float* a_w1   = (const float*)d_in[19];
  const float* a_b1   = (const float*)d_in[20];
  const float* a_w2   = (const float*)d_in[21];
  const float* a_b2   = (const float*)d_in[22];
  const float* base_w = (const float*)d_in[23];
  const float* base_b = (const float*)d_in[24];
  const float* gh_w1  = (const float*)d_in[25];
  const float* gh_b1  = (const float*)d_in[26];
  const float* gh_w2  = (const float*)d_in[27];
  const float* gh_b2  = (const float*)d_in[28];
  const float* ex_w1  = (const float*)d_in[29];
  const float* ex_b1  = (const float*)d_in[30];
  const float* ex_w2  = (const float*)d_in[31];
  const float* ex_b2  = (const float*)d_in[32];
  (void)in_sizes; (void)n_in; (void)out_size; (void)ws_size;

  char* ws = (char*)d_ws;
  size_t off = 0;
  auto alloc = [&](size_t bytes) { void* p = ws + off; off += (bytes + 255) & ~(size_t)255; return p; };

  unsigned short* w0v  = (unsigned short*)alloc((size_t)768 * 1024 * 2);
  unsigned short* w0u  = (unsigned short*)alloc((size_t)768 * 1024 * 2);
  unsigned short* w1t  = (unsigned short*)alloc((size_t)1024 * 704 * 2);
  unsigned short* wcat = (unsigned short*)alloc((size_t)3072 * 1024 * 2);
  float* bcat          = (float*)alloc((size_t)3072 * 4);
  unsigned short* Amat = (unsigned short*)alloc((size_t)2304 * 1024 * 2);
  float* TAB           = (float*)alloc((size_t)2304 * 768 * 4);
  float* nstat         = (float*)alloc((size_t)101 * 5 * 4);
  float* cstat         = (float*)alloc((size_t)2000 * 2 * 4);
  float* ucon          = (float*)alloc((size_t)704 * 4);
  unsigned short* uv   = (unsigned short*)alloc((size_t)B_SZ * 704 * 2);
  float* xfin          = (float*)alloc((size_t)B_SZ * 1024 * 4);
  float* hid_f         = (float*)alloc((size_t)B_SZ * 1024 * 4);
  unsigned short* hidb = (unsigned short*)alloc((size_t)B_SZ * 1024 * 2);
  unsigned short* H1   = (unsigned short*)alloc((size_t)B_SZ * 3072 * 2);

  const dim3 blk(256);
  const dim3 tblk(64, 4);

  // weight prep
  tpadT<<<dim3(16, 12), tblk, 0, stream>>>(lin0_w, w0v, 1350, 675, 675, 1024, 1024);
  tpadT<<<dim3(16, 12), tblk, 0, stream>>>(lin0_w, w0u, 1350, 0, 675, 1024, 1024);
  tpadT<<<dim3(11, 16), tblk, 0, stream>>>(lin1_w, w1t, 1024, 0, 1024, 675, 704);
  tpadT<<<dim3(16, 4), tblk, 0, stream>>>(r_w1, wcat, 256, 0, 256, 1024, 1024);
  tpadT<<<dim3(16, 4), tblk, 0, stream>>>(a_w1, wcat + (size_t)256 * 1024, 256, 0, 256, 1024, 1024);
  tpadT<<<dim3(16, 8), tblk, 0, stream>>>(gh_w1, wcat + (size_t)512 * 1024, 512, 0, 512, 1024, 1024);
  for (int e = 0; e < 4; e++)
    tpadT<<<dim3(16, 8), tblk, 0, stream>>>(ex_w1 + (size_t)e * 1024 * 512,
        wcat + (size_t)(1024 + e * 512) * 1024, 512, 0, 512, 1024, 1024);
  prep_bcat<<<12, blk, 0, stream>>>(r_b1, a_b1, gh_b1, ex_b1, bcat);

  // tables + stats
  build_amat<<<576, blk, 0, stream>>>(tok_w, tok_b, cat_emb, ln_g, ln_b, Amat);
  stats_rows<<<526, blk, 0, stream>>>(tok_w, tok_b, cat_emb, nstat, cstat);
  gemm_gl<3><<<18 * 6, blk, 0, stream>>>(Amat, 1024, w0v, 1024,
      nullptr, 0, nullptr, 6, 768, 768, TAB, nullptr);

  // constant u + fused v path -> uv
  u_const_k<<<176, blk, 0, stream>>>(w0u, nstat, tok_w, ln_g, ln_b, lin0_b, ucon);
  fused_v<<<B_SZ, dim3(512), 0, stream>>>(TAB, nstat, cstat, x_num, x_cat,
      sgu_ln_g, sgu_ln_b, sgu_w, sgu_b, lin0_b, ucon, uv);

  // tail
  gemm_gl<0><<<8 * 8, blk, 0, stream>>>(uv, 704, w1t, 704,
      lin1_b, 0, tok_w, 8, 1024, 1024, xfin, nullptr);
  ln_gelu_hidden<<<B_SZ / 4, blk, 0, stream>>>(xfin, ln_g, ln_b, hid_f, hidb);
  gemm_gl<1><<<8 * 24, blk, 0, stream>>>(hidb, 1024, wcat, 1024,
      bcat, 0, nullptr, 24, 3072, 3072, nullptr, H1);

  final_head<<<B_SZ, blk, 0, stream>>>(H1, hid_f, r_w2, r_b2, a_w2, a_b2, gh_w2, gh_b2,
                                       ex_w2, ex_b2, base_w, base_b, (float*)d_out);
}

// Round 5
// 178.230 us; speedup vs baseline: 7.0297x; 1.7536x over previous
//
#include <hip/hip_runtime.h>
#include <math.h>

#define B_SZ 1024

typedef __attribute__((ext_vector_type(8))) short bf16x8;
typedef __attribute__((ext_vector_type(4))) float f32x4;
typedef __attribute__((ext_vector_type(4))) float floatx4;
typedef __attribute__((ext_vector_type(4))) unsigned short ushortx4;

#define GLOAD16(src, dst) __builtin_amdgcn_global_load_lds( \
    (const __attribute__((address_space(1))) void*)(src), \
    (__attribute__((address_space(3))) void*)(dst), 16, 0, 0)

__device__ __forceinline__ unsigned short f2bf(float f) {
  unsigned int u = __float_as_uint(f);
  u += 0x7fff + ((u >> 16) & 1);
  return (unsigned short)(u >> 16);
}
__device__ __forceinline__ float bf2f(unsigned short b) {
  return __uint_as_float(((unsigned int)b) << 16);
}
__device__ __forceinline__ float gelu_exact(float x) {
  return 0.5f * x * (1.0f + erff(x * 0.70710678118654752f));
}
// tanh-form gelu: x - x/(exp2(z)+1), z = x*(c0 + c1*x^2); max |err| ~5e-4
__device__ __forceinline__ float gelu_fast(float x) {
  const float c0 = 2.3022586f;    // 2*log2e*sqrt(2/pi)
  const float c1 = 0.10295465f;   // c0*0.044715
  float z = x * __builtin_fmaf(x * x, c1, c0);
  float e = __builtin_amdgcn_exp2f(z);
  float r = __builtin_amdgcn_rcpf(e + 1.0f);
  return __builtin_fmaf(-x, r, x);
}
__device__ __forceinline__ float wred(float v) {
#pragma unroll
  for (int o = 32; o > 0; o >>= 1) v += __shfl_xor(v, o, 64);
  return v;
}

// ---------------- merged transpose jobs: f32[k][n] -> bf16[n][k] (zero padded) ----------------
struct TJobs {
  const float* src[10];
  unsigned short* dst[10];
  int ldin[10]; int coff[10]; int Nsrc[10]; int Ksrc[10]; int Kp[10];
  int nbx[10]; int blk0[11];
};

__global__ __launch_bounds__(256)
void tpad_multi(TJobs J)
{
  __shared__ float tile[64][65];
  const int bid = blockIdx.x;
  int j = 0;
  while (bid >= J.blk0[j + 1]) ++j;
  const int bx = bid - J.blk0[j];
  const int k0 = (bx % J.nbx[j]) * 64;
  const int n0 = (bx / J.nbx[j]) * 64;
  const float* in = J.src[j];
  unsigned short* out = J.dst[j];
  const int ldin = J.ldin[j], coff = J.coff[j], Nsrc = J.Nsrc[j], Ksrc = J.Ksrc[j], Kp = J.Kp[j];
  const int kx = threadIdx.x;
  const int ry = threadIdx.y;
  for (int r = ry; r < 64; r += 4) {
    const int k = k0 + r;
    const int n = n0 + kx;
    tile[r][kx] = (k < Ksrc && n < Nsrc) ? in[(size_t)k * ldin + coff + n] : 0.f;
  }
  __syncthreads();
  for (int r = ry; r < 64; r += 4) {
    const int n = n0 + r;
    const int k = k0 + kx;
    out[(size_t)n * Kp + k] = f2bf(tile[kx][r]);
  }
}

// ---------------- merged small prep: A-matrix rows + closed-form stats + bias concat ----------------
// A-matrix (2304 x 1024 bf16): r 0..100: tok_w[r]*g ; 101..200: tok_b[r-101]*g ;
// 201..2200: (cat_emb[j]+tok_b[100+j/100])*g ; 2201: g ; 2202: ln_b ; else 0
__global__ __launch_bounds__(256)
void prep_small(const float* __restrict__ tok_w, const float* __restrict__ tok_b,
                const float* __restrict__ cat_emb,
                const float* __restrict__ ln_g, const float* __restrict__ ln_b,
                const float* __restrict__ r_b1, const float* __restrict__ a_b1,
                const float* __restrict__ gh_b1, const float* __restrict__ ex_b1,
                unsigned short* __restrict__ Amat,
                float* __restrict__ nstat, float* __restrict__ cstat,
                float* __restrict__ bcat)
{
  const int bb = blockIdx.x;
  const int lane = threadIdx.x & 63;
  if (bb < 576) {
    const int r = bb * 4 + (threadIdx.x >> 6);
    if (r >= 2304) return;
    unsigned short* out = Amat + (size_t)r * 1024;
    for (int k = lane * 4; k < 1024; k += 256) {
      floatx4 g = *(const floatx4*)(ln_g + k);
      floatx4 v;
      if (r <= 100) {
        floatx4 a = *(const floatx4*)(tok_w + (size_t)r * 1024 + k);
#pragma unroll
        for (int q = 0; q < 4; q++) v[q] = a[q] * g[q];
      } else if (r <= 200) {
        floatx4 a = *(const floatx4*)(tok_b + (size_t)(r - 101) * 1024 + k);
#pragma unroll
        for (int q = 0; q < 4; q++) v[q] = a[q] * g[q];
      } else if (r <= 2200) {
        const int j = r - 201;
        const int c = j / 100;
        floatx4 a = *(const floatx4*)(cat_emb + (size_t)j * 1024 + k);
        floatx4 bq = *(const floatx4*)(tok_b + (size_t)(100 + c) * 1024 + k);
#pragma unroll
        for (int q = 0; q < 4; q++) v[q] = (a[q] + bq[q]) * g[q];
      } else if (r == 2201) {
        v = g;
      } else if (r == 2202) {
        v = *(const floatx4*)(ln_b + k);
      } else {
        v[0] = 0.f; v[1] = 0.f; v[2] = 0.f; v[3] = 0.f;
      }
      ushortx4 o;
#pragma unroll
      for (int q = 0; q < 4; q++) o[q] = f2bf(v[q]);
      *(ushortx4*)(out + k) = o;
    }
  } else if (bb < 1102) {
    const int w = (bb - 576) * 4 + (threadIdx.x >> 6);
    if (w >= 2101) return;
    if (w <= 100) {
      const int t = w;
      const float* wr = tok_w + (size_t)t * 1024;
      const float* br = (t >= 1) ? (tok_b + (size_t)(t - 1) * 1024) : nullptr;
      float sw = 0, sww = 0, sb = 0, sbb = 0, swb = 0;
      for (int k = lane * 4; k < 1024; k += 256) {
        floatx4 a = *(const floatx4*)(wr + k);
#pragma unroll
        for (int q = 0; q < 4; q++) { sw += a[q]; sww += a[q] * a[q]; }
        if (br) {
          floatx4 bq = *(const floatx4*)(br + k);
#pragma unroll
          for (int q = 0; q < 4; q++) { sb += bq[q]; sbb += bq[q] * bq[q]; swb += a[q] * bq[q]; }
        }
      }
      sw = wred(sw); sww = wred(sww); sb = wred(sb); sbb = wred(sbb); swb = wred(swb);
      if (lane == 0) {
        float* ns = nstat + (size_t)t * 5;
        ns[0] = sw; ns[1] = sww; ns[2] = sb; ns[3] = sbb; ns[4] = swb;
      }
    } else {
      const int j = w - 101;
      const int c = j / 100;
      const float* ar = cat_emb + (size_t)j * 1024;
      const float* br = tok_b + (size_t)(100 + c) * 1024;
      float s1 = 0, s2 = 0;
      for (int k = lane * 4; k < 1024; k += 256) {
        floatx4 a = *(const floatx4*)(ar + k);
        floatx4 bq = *(const floatx4*)(br + k);
#pragma unroll
        for (int q = 0; q < 4; q++) { const float v = a[q] + bq[q]; s1 += v; s2 += v * v; }
      }
      s1 = wred(s1); s2 = wred(s2);
      if (lane == 0) { cstat[(size_t)j * 2] = s1; cstat[(size_t)j * 2 + 1] = s2; }
    }
  } else {
    const int n = (bb - 1102) * 256 + threadIdx.x;
    if (n >= 3072) return;
    float v;
    if (n < 256) v = r_b1[n];
    else if (n < 512) v = a_b1[n - 256];
    else if (n < 1024) v = gh_b1[n - 512];
    else v = ex_b1[n - 1024];
    bcat[n] = v;
  }
}

// ---------------- generic bf16 GEMM, m97 structure ----------------
template<int EPI>
__global__ __launch_bounds__(256)
void gemm_gl(const unsigned short* __restrict__ A, long pitchA,
             const unsigned short* __restrict__ Bw, int K,
             const float* __restrict__ bias, int bias_off,
             const float* __restrict__ extra,
             int NB, int Nvalid, int ldo,
             float* __restrict__ outf, unsigned short* __restrict__ outb)
{
  __shared__ unsigned short As[128 * 32];
  __shared__ unsigned short Bs[128 * 32];
  const int tid = threadIdx.x, lane = tid & 63, wv = tid >> 6;
  const int bid = blockIdx.x;
  const int nb = bid % NB, mb = bid / NB;
  const int m0 = mb * 128, n0 = nb * 128;
  const int wr = (wv >> 1) << 6, wc = (wv & 1) << 6;
  const int fr = lane & 15, fq = lane >> 4;
  const int c0 = wv * 2;
  const int srow = lane >> 2;
  const int sk = (lane & 3) << 3;

  const unsigned short* a0 = A + (size_t)(m0 + c0 * 16 + srow) * pitchA + sk;
  const unsigned short* a1 = A + (size_t)(m0 + (c0 + 1) * 16 + srow) * pitchA + sk;
  const unsigned short* b0p = Bw + (size_t)(n0 + c0 * 16 + srow) * K + sk;
  const unsigned short* b1p = Bw + (size_t)(n0 + (c0 + 1) * 16 + srow) * K + sk;

  f32x4 acc[4][4] = {};
  for (int k0 = 0; k0 < K; k0 += 32) {
    __syncthreads();
    GLOAD16(a0 + k0, &As[c0 * 512]);
    GLOAD16(a1 + k0, &As[(c0 + 1) * 512]);
    GLOAD16(b0p + k0, &Bs[c0 * 512]);
    GLOAD16(b1p + k0, &Bs[(c0 + 1) * 512]);
    __syncthreads();
    bf16x8 af[4], bw_[4];
#pragma unroll
    for (int i = 0; i < 4; i++) {
      af[i]  = *(const bf16x8*)&As[(wr + i * 16 + fr) * 32 + fq * 8];
      bw_[i] = *(const bf16x8*)&Bs[(wc + i * 16 + fr) * 32 + fq * 8];
    }
#pragma unroll
    for (int i = 0; i < 4; i++)
#pragma unroll
      for (int j = 0; j < 4; j++)
        acc[i][j] = __builtin_amdgcn_mfma_f32_16x16x32_bf16(af[i], bw_[j], acc[i][j], 0, 0, 0);
  }

#pragma unroll
  for (int i = 0; i < 4; i++)
#pragma unroll
    for (int j = 0; j < 4; j++) {
      const int n = n0 + wc + j * 16 + fr;
      if (n >= ldo) continue;
      const bool valid = (n < Nvalid);
      const float bv = (EPI == 3) ? 0.f : (valid ? bias[bias_off + n] : 0.f);
      const float ev = (EPI == 0) ? extra[n] : 0.f;
#pragma unroll
      for (int q = 0; q < 4; q++) {
        const int m = m0 + wr + i * 16 + fq * 4 + q;
        const float a = acc[i][j][q];
        if (EPI == 0) {
          outf[(size_t)m * ldo + n] = a + bv + ev;
        } else if (EPI == 1) {
          outb[(size_t)m * ldo + n] = f2bf(fmaxf(a + bv, 0.f));
        } else {
          outf[(size_t)m * ldo + n] = a;
        }
      }
    }
}

// ---------------- constant u vector: gelu(LN(tok_w[0]) @ W_u + b_u) ----------------
__global__ __launch_bounds__(256)
void u_const_k(const unsigned short* __restrict__ w0u, const float* __restrict__ nstat,
               const float* __restrict__ tok_w, const float* __restrict__ ln_g,
               const float* __restrict__ ln_b, const float* __restrict__ lin0_b,
               float* __restrict__ ucon)
{
  __shared__ float xk[1024];
  const int tid = threadIdx.x, lane = tid & 63, wv = tid >> 6;
  const float m = nstat[0] * (1.f / 1024.f);
  const float ex2 = nstat[1] * (1.f / 1024.f);
  const float rs = rsqrtf(ex2 - m * m + 1e-5f);
  for (int k = tid; k < 1024; k += 256)
    xk[k] = bf2f(f2bf((tok_w[k] - m) * rs * ln_g[k] + ln_b[k]));
  __syncthreads();
  const int c = blockIdx.x * 4 + wv;
  if (c >= 704) return;
  if (c >= 675) { if (lane == 0) ucon[c] = 0.f; return; }
  const unsigned short* wr = w0u + (size_t)c * 1024;
  float s = 0.f;
  for (int k = lane; k < 1024; k += 64) s += bf2f(wr[k]) * xk[k];
  s = wred(s);
  if (lane == 0) ucon[c] = gelu_exact(s + lin0_b[c]);
}

// ---------------- fused v-path: single-pass, vectorized, fast-gelu ----------------
__global__ __launch_bounds__(512)
void fused_v(const float* __restrict__ TAB, const float* __restrict__ nstat,
             const float* __restrict__ cstat,
             const float* __restrict__ x_num, const int* __restrict__ x_cat,
             const float* __restrict__ sgu_ln_g, const float* __restrict__ sgu_ln_b,
             const float* __restrict__ sgu_w, const float* __restrict__ sgu_b,
             const float* __restrict__ lin0_b, const float* __restrict__ ucon,
             unsigned short* __restrict__ uv)
{
  const int b = blockIdx.x;
  const int tid = threadIdx.x, lane = tid & 63, wv = tid >> 6;
  __shared__ float Rls[768], Cls[768];
  __shared__ float alf[121], bet[121], gam[121], swt_s[121];
  __shared__ int   t1r[121], t2r[121];
  __shared__ float accw[8][768];
  __shared__ float kbw[8], wsw[8];

  for (int d = tid; d < 768; d += 512) {
    Rls[d] = (d < 675) ? TAB[(size_t)2201 * 768 + d] : 0.f;
    Cls[d] = (d < 675) ? (TAB[(size_t)2202 * 768 + d] + lin0_b[675 + d]) : 0.f;
  }
  if (tid < 121) {
    const int t = tid;
    float m, ex2, sc = 1.f;
    int i1, i2;
    float beflag;
    if (t <= 100) {
      const float* ns = nstat + (size_t)t * 5;
      sc = (t == 0) ? 1.f : x_num[b * 100 + t - 1];
      m = (sc * ns[0] + ns[2]) * (1.f / 1024.f);
      ex2 = (sc * sc * ns[1] + 2.f * sc * ns[4] + ns[3]) * (1.f / 1024.f);
      i1 = t; i2 = (t == 0) ? 2201 : (100 + t);
      beflag = (t == 0) ? 0.f : 1.f;
    } else {
      const int c = t - 101;
      const int j = x_cat[b * 20 + c] + 100 * c;
      m = cstat[(size_t)j * 2] * (1.f / 1024.f);
      ex2 = cstat[(size_t)j * 2 + 1] * (1.f / 1024.f);
      i1 = 201 + j; i2 = 2201; beflag = 0.f;
    }
    const float var = ex2 - m * m;
    const float rs = rsqrtf(var + 1e-5f);
    alf[t] = rs * sc;
    bet[t] = beflag * rs;
    gam[t] = -m * rs;
    t1r[t] = i1; t2r[t] = i2;
    swt_s[t] = sgu_w[t];
  }
  __syncthreads();

  // TAB cols >=675 are exactly zero (B rows zero-padded), Rls/Cls zeroed -> branchless
  float acc0[4] = {}, acc1[4] = {}, acc2[4] = {};
  float kb = 0.f, wsum = 0.f;
  const int dl = lane << 2;

  for (int i = 0; i < 16; i++) {
    const int t = wv + 8 * i;
    if (t >= 121) break;
    const float a = alf[t], be = bet[t], ga = gam[t];
    const float* T1 = TAB + (size_t)t1r[t] * 768;
    const float* T2 = TAB + (size_t)t2r[t] * 768;
    float s = 0.f, ss = 0.f;
    float v0[4], v1[4], v2[4];
#define CHUNK(vv, ch) { \
    const int d = (ch) * 256 + dl; \
    floatx4 t1 = *(const floatx4*)(T1 + d); \
    floatx4 t2 = *(const floatx4*)(T2 + d); \
    floatx4 rr = *(const floatx4*)(&Rls[d]); \
    floatx4 cc = *(const floatx4*)(&Cls[d]); \
    _Pragma("unroll") \
    for (int q = 0; q < 4; q++) { \
      const float pre = __builtin_fmaf(a, t1[q], __builtin_fmaf(be, t2[q], __builtin_fmaf(ga, rr[q], cc[q]))); \
      const float g = gelu_fast(pre); \
      vv[q] = g; s += g; ss += g * g; } }
    CHUNK(v0, 0) CHUNK(v1, 1) CHUNK(v2, 2)
#undef CHUNK
    s = wred(s); ss = wred(ss);
    const float mu = s * (1.f / 675.f);
    const float rho = rsqrtf(ss * (1.f / 675.f) - mu * mu + 1e-5f);
    const float sw = swt_s[t];
    const float wr_ = sw * rho;
#pragma unroll
    for (int q = 0; q < 4; q++) {
      acc0[q] = __builtin_fmaf(wr_, v0[q], acc0[q]);
      acc1[q] = __builtin_fmaf(wr_, v1[q], acc1[q]);
      acc2[q] = __builtin_fmaf(wr_, v2[q], acc2[q]);
    }
    kb = __builtin_fmaf(wr_, mu, kb);
    wsum += sw;
  }

  *(floatx4*)&accw[wv][dl]       = *(floatx4*)acc0;
  *(floatx4*)&accw[wv][256 + dl] = *(floatx4*)acc1;
  *(floatx4*)&accw[wv][512 + dl] = *(floatx4*)acc2;
  if (lane == 0) { kbw[wv] = kb; wsw[wv] = wsum; }
  __syncthreads();

  float kbs = 0.f, wss = 0.f;
#pragma unroll
  for (int w = 0; w < 8; w++) { kbs += kbw[w]; wss += wsw[w]; }
  const float sb0 = sgu_b[0];
  for (int d = tid; d < 704; d += 512) {
    unsigned short o = 0;
    if (d < 675) {
      float a = 0.f;
#pragma unroll
      for (int w = 0; w < 8; w++) a += accw[w][d];
      const float v0 = sgu_ln_g[d] * (a - kbs) + sgu_ln_b[d] * wss + sb0;
      o = f2bf(ucon[d] * v0);
    }
    uv[(size_t)b * 704 + d] = o;
  }
}

// ---------------- LN + gelu -> hidden (f32 + bf16) ----------------
__global__ __launch_bounds__(256)
void ln_gelu_hidden(const float* __restrict__ xfin,
                    const float* __restrict__ ln_g, const float* __restrict__ ln_b,
                    float* __restrict__ hid_f, unsigned short* __restrict__ hid_bf)
{
  const int w = (blockIdx.x * 256 + threadIdx.x) >> 6;
  const int lane = threadIdx.x & 63;
  if (w >= B_SZ) return;
  const float* row = xfin + (size_t)w * 1024;
  float s = 0.f, ss = 0.f;
  for (int k = lane; k < 1024; k += 64) { float v = row[k]; s += v; ss += v * v; }
  s = wred(s); ss = wred(ss);
  const float m = s * (1.f / 1024.f);
  const float var = ss * (1.f / 1024.f) - m * m;
  const float rs = rsqrtf(var + 1e-5f);
  for (int k = lane; k < 1024; k += 64) {
    float v = gelu_exact((row[k] - m) * rs * ln_g[k] + ln_b[k]);
    hid_f[(size_t)w * 1024 + k] = v;
    hid_bf[(size_t)w * 1024 + k] = f2bf(v);
  }
}

// ---------------- per-row finale ----------------
__global__ __launch_bounds__(256)
void final_head(const unsigned short* __restrict__ H1, const float* __restrict__ hid_f,
                const float* __restrict__ r_w2, const float* __restrict__ r_b2,
                const float* __restrict__ a_w2, const float* __restrict__ a_b2,
                const float* __restrict__ gh_w2, const float* __restrict__ gh_b2,
                const float* __restrict__ ex_w2, const float* __restrict__ ex_b2,
                const float* __restrict__ base_w, const float* __restrict__ base_b,
                float* __restrict__ out)
{
  const int b = blockIdx.x;
  const int tid = threadIdx.x;
  const unsigned short* h1 = H1 + (size_t)b * 3072;
  float p[11];
#pragma unroll
  for (int i = 0; i < 11; i++) p[i] = 0.f;
  {
    const int m = tid;
    const float hr = bf2f(h1[m]);
    p[0] = hr * r_w2[m * 4 + 0];
    p[1] = hr * r_w2[m * 4 + 1];
    p[2] = hr * r_w2[m * 4 + 2];
    p[3] = hr * r_w2[m * 4 + 3];
    const float ha = bf2f(h1[256 + m]);
    p[4] = ha * a_w2[m];
  }
  for (int m = tid; m < 512; m += 256) {
    p[5] += bf2f(h1[512 + m]) * gh_w2[m];
#pragma unroll
    for (int e = 0; e < 4; e++)
      p[6 + e] += bf2f(h1[1024 + e * 512 + m]) * ex_w2[e * 512 + m];
  }
  for (int k = tid; k < 1024; k += 256) p[10] += hid_f[(size_t)b * 1024 + k] * base_w[k];

  __shared__ float red[11][4];
  const int lane = tid & 63, wv = tid >> 6;
#pragma unroll
  for (int i = 0; i < 11; i++) {
    const float v = wred(p[i]);
    if (lane == 0) red[i][wv] = v;
  }
  __syncthreads();
  if (tid == 0) {
    float s[11];
#pragma unroll
    for (int i = 0; i < 11; i++) s[i] = red[i][0] + red[i][1] + red[i][2] + red[i][3];
    float lg[4];
#pragma unroll
    for (int e = 0; e < 4; e++) lg[e] = s[e] + r_b2[e];
    const float mx = fmaxf(fmaxf(lg[0], lg[1]), fmaxf(lg[2], lg[3]));
    float den[4]; float dsum = 0.f;
#pragma unroll
    for (int e = 0; e < 4; e++) { den[e] = expf(lg[e] - mx); dsum += den[e]; }
#pragma unroll
    for (int e = 0; e < 4; e++) den[e] /= dsum;
    int i1 = 0;
    for (int e = 1; e < 4; e++) if (den[e] > den[i1]) i1 = e;
    int i2 = -1;
    for (int e = 0; e < 4; e++) { if (e == i1) continue; if (i2 < 0 || den[e] > den[i2]) i2 = e; }
    float eo[4];
#pragma unroll
    for (int e = 0; e < 4; e++) eo[e] = s[6 + e] + ex_b2[e];
    const float v1 = den[i1], v2 = den[i2];
    const float ssum = fmaxf(v1 + v2, 1e-8f);
    const float local = (v1 * eo[i1] + v2 * eo[i2]) / ssum;
    const float glob = s[5] + gh_b2[0];
    const float alpha = 1.0f / (1.0f + expf(-(s[4] + a_b2[0])));
    out[b] = s[10] + base_b[0] + alpha * (glob + local);
  }
}

extern "C" void kernel_launch(void* const* d_in, const int* in_sizes, int n_in,
                              void* d_out, int out_size, void* d_ws, size_t ws_size,
                              hipStream_t stream)
{
  const float* x_num  = (const float*)d_in[0];
  const int*   x_cat  = (const int*)d_in[1];
  const float* tok_w  = (const float*)d_in[2];
  const float* tok_b  = (const float*)d_in[3];
  const float* cat_emb= (const float*)d_in[4];
  const float* ln_g   = (const float*)d_in[5];
  const float* ln_b   = (const float*)d_in[6];
  const float* lin0_w = (const float*)d_in[7];
  const float* lin0_b = (const float*)d_in[8];
  const float* sgu_ln_g = (const float*)d_in[9];
  const float* sgu_ln_b = (const float*)d_in[10];
  const float* sgu_w  = (const float*)d_in[11];
  const float* sgu_b  = (const float*)d_in[12];
  const float* lin1_w = (const float*)d_in[13];
  const float* lin1_b = (const float*)d_in[14];
  const float* r_w1   = (const float*)d_in[15];
  const float* r_b1   = (const float*)d_in[16];
  const float* r_w2   = (const float*)d_in[17];
  const float* r_b2   = (const float*)d_in[18];
  const float* a_w1   = (const float*)d_in[19];
  const float* a_b1   = (const float*)d_in[20];
  const float* a_w2   = (const float*)d_in[21];
  const float* a_b2   = (const float*)d_in[22];
  const float* base_w = (const float*)d_in[23];
  const float* base_b = (const float*)d_in[24];
  const float* gh_w1  = (const float*)d_in[25];
  const float* gh_b1  = (const float*)d_in[26];
  const float* gh_w2  = (const float*)d_in[27];
  const float* gh_b2  = (const float*)d_in[28];
  const float* ex_w1  = (const float*)d_in[29];
  const float* ex_b1  = (const float*)d_in[30];
  const float* ex_w2  = (const float*)d_in[31];
  const float* ex_b2  = (const float*)d_in[32];
  (void)in_sizes; (void)n_in; (void)out_size; (void)ws_size;

  char* ws = (char*)d_ws;
  size_t off = 0;
  auto alloc = [&](size_t bytes) { void* p = ws + off; off += (bytes + 255) & ~(size_t)255; return p; };

  unsigned short* w0v  = (unsigned short*)alloc((size_t)768 * 1024 * 2);
  unsigned short* w0u  = (unsigned short*)alloc((size_t)768 * 1024 * 2);
  unsigned short* w1t  = (unsigned short*)alloc((size_t)1024 * 704 * 2);
  unsigned short* wcat = (unsigned short*)alloc((size_t)3072 * 1024 * 2);
  float* bcat          = (float*)alloc((size_t)3072 * 4);
  unsigned short* Amat = (unsigned short*)alloc((size_t)2304 * 1024 * 2);
  float* TAB           = (float*)alloc((size_t)2304 * 768 * 4);
  float* nstat         = (float*)alloc((size_t)101 * 5 * 4);
  float* cstat         = (float*)alloc((size_t)2000 * 2 * 4);
  float* ucon          = (float*)alloc((size_t)704 * 4);
  unsigned short* uv   = (unsigned short*)alloc((size_t)B_SZ * 704 * 2);
  float* xfin          = (float*)alloc((size_t)B_SZ * 1024 * 4);
  float* hid_f         = (float*)alloc((size_t)B_SZ * 1024 * 4);
  unsigned short* hidb = (unsigned short*)alloc((size_t)B_SZ * 1024 * 2);
  unsigned short* H1   = (unsigned short*)alloc((size_t)B_SZ * 3072 * 2);

  const dim3 blk(256);
  const dim3 tblk(64, 4);

  // merged weight transposes: 10 jobs, one launch
  TJobs J;
  auto setJ = [&](int i, const float* s, unsigned short* d, int ldin, int coff,
                  int Nsrc, int Ksrc, int Kp, int nbx, int nby) {
    J.src[i] = s; J.dst[i] = d; J.ldin[i] = ldin; J.coff[i] = coff;
    J.Nsrc[i] = Nsrc; J.Ksrc[i] = Ksrc; J.Kp[i] = Kp; J.nbx[i] = nbx;
    J.blk0[i + 1] = J.blk0[i] + nbx * nby;
  };
  J.blk0[0] = 0;
  setJ(0, lin0_w, w0v, 1350, 675, 675, 1024, 1024, 16, 12);
  setJ(1, lin0_w, w0u, 1350, 0,   675, 1024, 1024, 16, 12);
  setJ(2, lin1_w, w1t, 1024, 0,  1024,  675,  704, 11, 16);
  setJ(3, r_w1,  wcat,                          256, 0, 256, 1024, 1024, 16, 4);
  setJ(4, a_w1,  wcat + (size_t)256 * 1024,     256, 0, 256, 1024, 1024, 16, 4);
  setJ(5, gh_w1, wcat + (size_t)512 * 1024,     512, 0, 512, 1024, 1024, 16, 8);
  for (int e = 0; e < 4; e++)
    setJ(6 + e, ex_w1 + (size_t)e * 1024 * 512,
         wcat + (size_t)(1024 + e * 512) * 1024, 512, 0, 512, 1024, 1024, 16, 8);
  tpad_multi<<<J.blk0[10], tblk, 0, stream>>>(J);

  // merged small prep: Amat + stats + bcat
  prep_small<<<1114, blk, 0, stream>>>(tok_w, tok_b, cat_emb, ln_g, ln_b,
      r_b1, a_b1, gh_b1, ex_b1, Amat, nstat, cstat, bcat);

  // table GEMM
  gemm_gl<3><<<18 * 6, blk, 0, stream>>>(Amat, 1024, w0v, 1024,
      nullptr, 0, nullptr, 6, 768, 768, TAB, nullptr);

  // constant u + fused v path -> uv
  u_const_k<<<176, blk, 0, stream>>>(w0u, nstat, tok_w, ln_g, ln_b, lin0_b, ucon);
  fused_v<<<B_SZ, dim3(512), 0, stream>>>(TAB, nstat, cstat, x_num, x_cat,
      sgu_ln_g, sgu_ln_b, sgu_w, sgu_b, lin0_b, ucon, uv);

  // tail
  gemm_gl<0><<<8 * 8, blk, 0, stream>>>(uv, 704, w1t, 704,
      lin1_b, 0, tok_w, 8, 1024, 1024, xfin, nullptr);
  ln_gelu_hidden<<<B_SZ / 4, blk, 0, stream>>>(xfin, ln_g, ln_b, hid_f, hidb);
  gemm_gl<1><<<8 * 24, blk, 0, stream>>>(hidb, 1024, wcat, 1024,
      bcat, 0, nullptr, 24, 3072, 3072, nullptr, H1);

  final_head<<<B_SZ, blk, 0, stream>>>(H1, hid_f, r_w2, r_b2, a_w2, a_b2, gh_w2, gh_b2,
                                       ex_w2, ex_b2, base_w, base_b, (float*)d_out);
}

// Round 6
// 152.081 us; speedup vs baseline: 8.2384x; 1.1719x over previous
//
#include <hip/hip_runtime.h>
#include <math.h>

#define B_SZ 1024

typedef __attribute__((ext_vector_type(8))) short bf16x8;
typedef __attribute__((ext_vector_type(4))) float f32x4;
typedef __attribute__((ext_vector_type(4))) float floatx4;
typedef __attribute__((ext_vector_type(4))) unsigned short ushortx4;

#define GLOAD16(src, dst) __builtin_amdgcn_global_load_lds( \
    (const __attribute__((address_space(1))) void*)(src), \
    (__attribute__((address_space(3))) void*)(dst), 16, 0, 0)

__device__ __forceinline__ unsigned short f2bf(float f) {
  unsigned int u = __float_as_uint(f);
  u += 0x7fff + ((u >> 16) & 1);
  return (unsigned short)(u >> 16);
}
__device__ __forceinline__ float bf2f(unsigned short b) {
  return __uint_as_float(((unsigned int)b) << 16);
}
__device__ __forceinline__ float gelu_exact(float x) {
  return 0.5f * x * (1.0f + erff(x * 0.70710678118654752f));
}
// tanh-form gelu: x - x/(exp2(z)+1), z = x*(c0 + c1*x^2); max |err| ~5e-4
__device__ __forceinline__ float gelu_fast(float x) {
  const float c0 = 2.3022586f;
  const float c1 = 0.10295465f;
  float z = x * __builtin_fmaf(x * x, c1, c0);
  float e = __builtin_amdgcn_exp2f(z);
  float r = __builtin_amdgcn_rcpf(e + 1.0f);
  return __builtin_fmaf(-x, r, x);
}
__device__ __forceinline__ float wred(float v) {
#pragma unroll
  for (int o = 32; o > 0; o >>= 1) v += __shfl_xor(v, o, 64);
  return v;
}

// ---------------- merged prep: 10 transpose jobs + Amat + stats + bcat ----------------
struct PrepArgs {
  const float* src[10];
  unsigned short* dst[10];
  int ldin[10]; int coff[10]; int Nsrc[10]; int Ksrc[10]; int Kp[10];
  int nbx[10]; int blk0[11];
};

__global__ __launch_bounds__(256)
void prep_all(PrepArgs J,
              const float* __restrict__ tok_w, const float* __restrict__ tok_b,
              const float* __restrict__ cat_emb,
              const float* __restrict__ ln_g, const float* __restrict__ ln_b,
              const float* __restrict__ r_b1, const float* __restrict__ a_b1,
              const float* __restrict__ gh_b1, const float* __restrict__ ex_b1,
              unsigned short* __restrict__ Amat,
              float* __restrict__ nstat, float* __restrict__ cstat,
              float* __restrict__ bcat)
{
  const int bid = blockIdx.x;
  const int tid = threadIdx.x;
  const int lane = tid & 63;
  const int NT = J.blk0[10];                 // 1328
  if (bid < NT) {
    __shared__ float tile[64][65];
    int j = 0;
    while (bid >= J.blk0[j + 1]) ++j;
    const int bx = bid - J.blk0[j];
    const int k0 = (bx % J.nbx[j]) * 64;
    const int n0 = (bx / J.nbx[j]) * 64;
    const float* in = J.src[j];
    unsigned short* out = J.dst[j];
    const int ldin = J.ldin[j], coff = J.coff[j], Nsrc = J.Nsrc[j], Ksrc = J.Ksrc[j], Kp = J.Kp[j];
    const int kx = tid & 63;
    const int ry = tid >> 6;
    for (int r = ry; r < 64; r += 4) {
      const int k = k0 + r;
      const int n = n0 + kx;
      tile[r][kx] = (k < Ksrc && n < Nsrc) ? in[(size_t)k * ldin + coff + n] : 0.f;
    }
    __syncthreads();
    for (int r = ry; r < 64; r += 4) {
      const int n = n0 + r;
      const int k = k0 + kx;
      out[(size_t)n * Kp + k] = f2bf(tile[kx][r]);
    }
  } else if (bid < NT + 576) {
    const int r = (bid - NT) * 4 + (tid >> 6);
    if (r >= 2304) return;
    unsigned short* out = Amat + (size_t)r * 1024;
    for (int k = lane * 4; k < 1024; k += 256) {
      floatx4 g = *(const floatx4*)(ln_g + k);
      floatx4 v;
      if (r <= 100) {
        floatx4 a = *(const floatx4*)(tok_w + (size_t)r * 1024 + k);
#pragma unroll
        for (int q = 0; q < 4; q++) v[q] = a[q] * g[q];
      } else if (r <= 200) {
        floatx4 a = *(const floatx4*)(tok_b + (size_t)(r - 101) * 1024 + k);
#pragma unroll
        for (int q = 0; q < 4; q++) v[q] = a[q] * g[q];
      } else if (r <= 2200) {
        const int j = r - 201;
        const int c = j / 100;
        floatx4 a = *(const floatx4*)(cat_emb + (size_t)j * 1024 + k);
        floatx4 bq = *(const floatx4*)(tok_b + (size_t)(100 + c) * 1024 + k);
#pragma unroll
        for (int q = 0; q < 4; q++) v[q] = (a[q] + bq[q]) * g[q];
      } else if (r == 2201) {
        v = g;
      } else if (r == 2202) {
        v = *(const floatx4*)(ln_b + k);
      } else {
        v[0] = 0.f; v[1] = 0.f; v[2] = 0.f; v[3] = 0.f;
      }
      ushortx4 o;
#pragma unroll
      for (int q = 0; q < 4; q++) o[q] = f2bf(v[q]);
      *(ushortx4*)(out + k) = o;
    }
  } else if (bid < NT + 576 + 526) {
    const int w = (bid - NT - 576) * 4 + (tid >> 6);
    if (w >= 2101) return;
    if (w <= 100) {
      const int t = w;
      const float* wr = tok_w + (size_t)t * 1024;
      const float* br = (t >= 1) ? (tok_b + (size_t)(t - 1) * 1024) : nullptr;
      float sw = 0, sww = 0, sb = 0, sbb = 0, swb = 0;
      for (int k = lane * 4; k < 1024; k += 256) {
        floatx4 a = *(const floatx4*)(wr + k);
#pragma unroll
        for (int q = 0; q < 4; q++) { sw += a[q]; sww += a[q] * a[q]; }
        if (br) {
          floatx4 bq = *(const floatx4*)(br + k);
#pragma unroll
          for (int q = 0; q < 4; q++) { sb += bq[q]; sbb += bq[q] * bq[q]; swb += a[q] * bq[q]; }
        }
      }
      sw = wred(sw); sww = wred(sww); sb = wred(sb); sbb = wred(sbb); swb = wred(swb);
      if (lane == 0) {
        float* ns = nstat + (size_t)t * 5;
        ns[0] = sw; ns[1] = sww; ns[2] = sb; ns[3] = sbb; ns[4] = swb;
      }
    } else {
      const int j = w - 101;
      const int c = j / 100;
      const float* ar = cat_emb + (size_t)j * 1024;
      const float* br = tok_b + (size_t)(100 + c) * 1024;
      float s1 = 0, s2 = 0;
      for (int k = lane * 4; k < 1024; k += 256) {
        floatx4 a = *(const floatx4*)(ar + k);
        floatx4 bq = *(const floatx4*)(br + k);
#pragma unroll
        for (int q = 0; q < 4; q++) { const float v = a[q] + bq[q]; s1 += v; s2 += v * v; }
      }
      s1 = wred(s1); s2 = wred(s2);
      if (lane == 0) { cstat[(size_t)j * 2] = s1; cstat[(size_t)j * 2 + 1] = s2; }
    }
  } else {
    const int n = (bid - NT - 1102) * 256 + tid;
    if (n >= 3072) return;
    float v;
    if (n < 256) v = r_b1[n];
    else if (n < 512) v = a_b1[n - 256];
    else if (n < 1024) v = gh_b1[n - 512];
    else v = ex_b1[n - 1024];
    bcat[n] = v;
  }
}

// ---------------- generic bf16 GEMM body, m97 structure ----------------
template<int EPI>
__device__ __forceinline__
void gemm_body(int bid, const unsigned short* __restrict__ A, long pitchA,
               const unsigned short* __restrict__ Bw, int K,
               const float* __restrict__ bias, int bias_off,
               const float* __restrict__ extra,
               int NB, int Nvalid, int ldo,
               float* __restrict__ outf, unsigned short* __restrict__ outb)
{
  __shared__ unsigned short As[128 * 32];
  __shared__ unsigned short Bs[128 * 32];
  const int tid = threadIdx.x, lane = tid & 63, wv = tid >> 6;
  const int nb = bid % NB, mb = bid / NB;
  const int m0 = mb * 128, n0 = nb * 128;
  const int wr = (wv >> 1) << 6, wc = (wv & 1) << 6;
  const int fr = lane & 15, fq = lane >> 4;
  const int c0 = wv * 2;
  const int srow = lane >> 2;
  const int sk = (lane & 3) << 3;

  const unsigned short* a0 = A + (size_t)(m0 + c0 * 16 + srow) * pitchA + sk;
  const unsigned short* a1 = A + (size_t)(m0 + (c0 + 1) * 16 + srow) * pitchA + sk;
  const unsigned short* b0p = Bw + (size_t)(n0 + c0 * 16 + srow) * K + sk;
  const unsigned short* b1p = Bw + (size_t)(n0 + (c0 + 1) * 16 + srow) * K + sk;

  f32x4 acc[4][4] = {};
  for (int k0 = 0; k0 < K; k0 += 32) {
    __syncthreads();
    GLOAD16(a0 + k0, &As[c0 * 512]);
    GLOAD16(a1 + k0, &As[(c0 + 1) * 512]);
    GLOAD16(b0p + k0, &Bs[c0 * 512]);
    GLOAD16(b1p + k0, &Bs[(c0 + 1) * 512]);
    __syncthreads();
    bf16x8 af[4], bw_[4];
#pragma unroll
    for (int i = 0; i < 4; i++) {
      af[i]  = *(const bf16x8*)&As[(wr + i * 16 + fr) * 32 + fq * 8];
      bw_[i] = *(const bf16x8*)&Bs[(wc + i * 16 + fr) * 32 + fq * 8];
    }
#pragma unroll
    for (int i = 0; i < 4; i++)
#pragma unroll
      for (int j = 0; j < 4; j++)
        acc[i][j] = __builtin_amdgcn_mfma_f32_16x16x32_bf16(af[i], bw_[j], acc[i][j], 0, 0, 0);
  }

#pragma unroll
  for (int i = 0; i < 4; i++)
#pragma unroll
    for (int j = 0; j < 4; j++) {
      const int n = n0 + wc + j * 16 + fr;
      if (n >= ldo) continue;
      const bool valid = (n < Nvalid);
      const float bv = (EPI == 3) ? 0.f : (valid ? bias[bias_off + n] : 0.f);
      const float ev = (EPI == 0) ? extra[n] : 0.f;
#pragma unroll
      for (int q = 0; q < 4; q++) {
        const int m = m0 + wr + i * 16 + fq * 4 + q;
        const float a = acc[i][j][q];
        if (EPI == 0) {
          outf[(size_t)m * ldo + n] = a + bv + ev;
        } else if (EPI == 1) {
          outb[(size_t)m * ldo + n] = f2bf(fmaxf(a + bv, 0.f));
        } else {
          outf[(size_t)m * ldo + n] = a;
        }
      }
    }
}

template<int EPI>
__global__ __launch_bounds__(256)
void gemm_gl(const unsigned short* __restrict__ A, long pitchA,
             const unsigned short* __restrict__ Bw, int K,
             const float* __restrict__ bias, int bias_off,
             const float* __restrict__ extra,
             int NB, int Nvalid, int ldo,
             float* __restrict__ outf, unsigned short* __restrict__ outb)
{
  gemm_body<EPI>(blockIdx.x, A, pitchA, Bw, K, bias, bias_off, extra, NB, Nvalid, ldo, outf, outb);
}

// ---------------- u_const body ----------------
__device__ __forceinline__
void u_const_body(int bid, const unsigned short* __restrict__ w0u, const float* __restrict__ nstat,
                  const float* __restrict__ tok_w, const float* __restrict__ ln_g,
                  const float* __restrict__ ln_b, const float* __restrict__ lin0_b,
                  float* __restrict__ ucon)
{
  __shared__ float xk[1024];
  const int tid = threadIdx.x, lane = tid & 63, wv = tid >> 6;
  const float m = nstat[0] * (1.f / 1024.f);
  const float ex2 = nstat[1] * (1.f / 1024.f);
  const float rs = rsqrtf(ex2 - m * m + 1e-5f);
  for (int k = tid; k < 1024; k += 256)
    xk[k] = bf2f(f2bf((tok_w[k] - m) * rs * ln_g[k] + ln_b[k]));
  __syncthreads();
  const int c = bid * 4 + wv;
  if (c >= 704) return;
  if (c >= 675) { if (lane == 0) ucon[c] = 0.f; return; }
  const unsigned short* wr = w0u + (size_t)c * 1024;
  float s = 0.f;
  for (int k = lane; k < 1024; k += 64) s += bf2f(wr[k]) * xk[k];
  s = wred(s);
  if (lane == 0) ucon[c] = gelu_exact(s + lin0_b[c]);
}

// table GEMM (108 blocks) + u_const (176 blocks) in one launch
__global__ __launch_bounds__(256)
void tab_and_u(const unsigned short* __restrict__ Amat, const unsigned short* __restrict__ w0v,
               float* __restrict__ TAB,
               const unsigned short* __restrict__ w0u, const float* __restrict__ nstat,
               const float* __restrict__ tok_w, const float* __restrict__ ln_g,
               const float* __restrict__ ln_b, const float* __restrict__ lin0_b,
               float* __restrict__ ucon)
{
  if (blockIdx.x < 108)
    gemm_body<3>(blockIdx.x, Amat, 1024, w0v, 1024, nullptr, 0, nullptr, 6, 768, 768, TAB, nullptr);
  else
    u_const_body(blockIdx.x - 108, w0u, nstat, tok_w, ln_g, ln_b, lin0_b, ucon);
}

// ---------------- input-independent rows: 2000 categorical + t0, gelu'd + (mu,rho) ----------------
__global__ __launch_bounds__(256)
void cat_rows(const float* __restrict__ TAB, const float* __restrict__ nstat,
              const float* __restrict__ cstat, const float* __restrict__ lin0_b,
              float* __restrict__ catval, float* __restrict__ catsc)
{
  const int r = blockIdx.x * 4 + (threadIdx.x >> 6);
  const int lane = threadIdx.x & 63;
  if (r >= 2001) return;
  float m, ex2;
  const float* T1;
  if (r < 2000) {
    m = cstat[(size_t)r * 2] * (1.f / 1024.f);
    ex2 = cstat[(size_t)r * 2 + 1] * (1.f / 1024.f);
    T1 = TAB + (size_t)(201 + r) * 768;
  } else {
    m = nstat[0] * (1.f / 1024.f);
    ex2 = nstat[1] * (1.f / 1024.f);
    T1 = TAB;
  }
  const float rs = rsqrtf(ex2 - m * m + 1e-5f);
  const float ga = -m * rs;
  const float* R = TAB + (size_t)2201 * 768;
  const float* C = TAB + (size_t)2202 * 768;
  const int dl = lane << 2;
  float s = 0.f, ss = 0.f;
  float* outp = catval + (size_t)r * 768;
#pragma unroll
  for (int ch = 0; ch < 3; ch++) {
    const int d = ch * 256 + dl;
    floatx4 t1 = *(const floatx4*)(T1 + d);
    floatx4 rr = *(const floatx4*)(R + d);
    floatx4 cc = *(const floatx4*)(C + d);
    floatx4 o;
#pragma unroll
    for (int q = 0; q < 4; q++) {
      const int dd = d + q;
      const float c2 = (dd < 675) ? (cc[q] + lin0_b[675 + dd]) : 0.f;
      const float pre = __builtin_fmaf(rs, t1[q], __builtin_fmaf(ga, rr[q], c2));
      const float g = (dd < 675) ? gelu_fast(pre) : 0.f;
      o[q] = g; s += g; ss = __builtin_fmaf(g, g, ss);
    }
    *(floatx4*)(outp + d) = o;
  }
  s = wred(s); ss = wred(ss);
  const float mu = s * (1.f / 675.f);
  const float rho = rsqrtf(ss * (1.f / 675.f) - mu * mu + 1e-5f);
  if (lane == 0) { catsc[(size_t)r * 2] = mu; catsc[(size_t)r * 2 + 1] = rho; }
}

// ---------------- fused v-path v2: 2 batch rows / block, cat rows gathered ----------------
__global__ __launch_bounds__(512)
void fused_v2(const float* __restrict__ TAB, const float* __restrict__ nstat,
              const float* __restrict__ catsc, const float* __restrict__ catval,
              const float* __restrict__ x_num, const int* __restrict__ x_cat,
              const float* __restrict__ sgu_ln_g, const float* __restrict__ sgu_ln_b,
              const float* __restrict__ sgu_w, const float* __restrict__ sgu_b,
              const float* __restrict__ lin0_b, const float* __restrict__ ucon,
              unsigned short* __restrict__ uv)
{
  const int b0 = blockIdx.x, b1 = blockIdx.x + 512;
  const int tid = threadIdx.x, lane = tid & 63, wv = tid >> 6;
  __shared__ float Rls[768], Cls[768];
  __shared__ float alf[2][100], bet[2][100], gam[2][100], swt[100];
  __shared__ float wrc[2][21], catkb[2][21];
  __shared__ int catrowS[2][21];
  __shared__ float accw[8][768];
  __shared__ float kbw[2][8];
  __shared__ float wss_s;

  for (int d = tid; d < 768; d += 512) {
    Rls[d] = (d < 675) ? TAB[(size_t)2201 * 768 + d] : 0.f;
    Cls[d] = (d < 675) ? (TAB[(size_t)2202 * 768 + d] + lin0_b[675 + d]) : 0.f;
  }
  if (tid < 200) {
    const int bb = tid / 100, tt = tid % 100;
    const int b = bb ? b1 : b0;
    const float sc = x_num[b * 100 + tt];
    const float* ns = nstat + (size_t)(tt + 1) * 5;
    const float m = (sc * ns[0] + ns[2]) * (1.f / 1024.f);
    const float ex2 = (sc * sc * ns[1] + 2.f * sc * ns[4] + ns[3]) * (1.f / 1024.f);
    const float rs = rsqrtf(ex2 - m * m + 1e-5f);
    alf[bb][tt] = rs * sc; bet[bb][tt] = rs; gam[bb][tt] = -m * rs;
    if (bb == 0) swt[tt] = sgu_w[tt + 1];
  } else if (tid < 242) {
    const int idx = tid - 200;
    const int bb = idx / 21, ii = idx % 21;
    const int b = bb ? b1 : b0;
    int row; float sw;
    if (ii < 20) { row = x_cat[b * 20 + ii] + 100 * ii; sw = sgu_w[101 + ii]; }
    else { row = 2000; sw = sgu_w[0]; }
    const float mu = catsc[(size_t)row * 2], rho = catsc[(size_t)row * 2 + 1];
    const float wr = sw * rho;
    wrc[bb][ii] = wr; catkb[bb][ii] = wr * mu; catrowS[bb][ii] = row;
  } else if (tid >= 256 && tid < 320) {
    float s = (lane < 121 ? sgu_w[lane] : 0.f) + (lane + 64 < 121 ? sgu_w[lane + 64] : 0.f);
    s = wred(s);
    if (lane == 0) wss_s = s;
  }
  __syncthreads();

  float accA[12] = {}, accB[12] = {};
  float kbA = 0.f, kbB = 0.f;
  const int dl = lane << 2;

  for (int i = 0; i < 13; i++) {
    const int tt = wv + 8 * i;
    if (tt >= 100) break;
    const float a0 = alf[0][tt], be0 = bet[0][tt], ga0 = gam[0][tt];
    const float a1 = alf[1][tt], be1 = bet[1][tt], ga1 = gam[1][tt];
    const float* T1 = TAB + (size_t)(tt + 1) * 768;
    const float* T2 = TAB + (size_t)(101 + tt) * 768;
    float s0 = 0.f, ss0 = 0.f, s1 = 0.f, ss1 = 0.f;
    float va[12], vb[12];
#pragma unroll
    for (int ch = 0; ch < 3; ch++) {
      const int d = ch * 256 + dl;
      floatx4 t1 = *(const floatx4*)(T1 + d);
      floatx4 t2 = *(const floatx4*)(T2 + d);
      floatx4 rr = *(const floatx4*)(&Rls[d]);
      floatx4 cc = *(const floatx4*)(&Cls[d]);
#pragma unroll
      for (int q = 0; q < 4; q++) {
        const float pre0 = __builtin_fmaf(a0, t1[q], __builtin_fmaf(be0, t2[q], __builtin_fmaf(ga0, rr[q], cc[q])));
        const float g0 = gelu_fast(pre0);
        va[ch * 4 + q] = g0; s0 += g0; ss0 = __builtin_fmaf(g0, g0, ss0);
        const float pre1 = __builtin_fmaf(a1, t1[q], __builtin_fmaf(be1, t2[q], __builtin_fmaf(ga1, rr[q], cc[q])));
        const float g1 = gelu_fast(pre1);
        vb[ch * 4 + q] = g1; s1 += g1; ss1 = __builtin_fmaf(g1, g1, ss1);
      }
    }
    s0 = wred(s0); ss0 = wred(ss0); s1 = wred(s1); ss1 = wred(ss1);
    const float sw = swt[tt];
    const float mu0 = s0 * (1.f / 675.f);
    const float rho0 = rsqrtf(ss0 * (1.f / 675.f) - mu0 * mu0 + 1e-5f);
    const float w0 = sw * rho0;
    const float mu1 = s1 * (1.f / 675.f);
    const float rho1 = rsqrtf(ss1 * (1.f / 675.f) - mu1 * mu1 + 1e-5f);
    const float w1 = sw * rho1;
#pragma unroll
    for (int q = 0; q < 12; q++) {
      accA[q] = __builtin_fmaf(w0, va[q], accA[q]);
      accB[q] = __builtin_fmaf(w1, vb[q], accB[q]);
    }
    kbA = __builtin_fmaf(w0, mu0, kbA);
    kbB = __builtin_fmaf(w1, mu1, kbB);
  }

  // gather precomputed cat + t0 rows
  for (int i = 0; i < 3; i++) {
    const int ii = wv + 8 * i;
    if (ii >= 21) break;
    {
      const float wr = wrc[0][ii];
      const float* cv = catval + (size_t)catrowS[0][ii] * 768;
#pragma unroll
      for (int ch = 0; ch < 3; ch++) {
        floatx4 v = *(const floatx4*)(cv + ch * 256 + dl);
#pragma unroll
        for (int q = 0; q < 4; q++) accA[ch * 4 + q] = __builtin_fmaf(wr, v[q], accA[ch * 4 + q]);
      }
    }
    {
      const float wr = wrc[1][ii];
      const float* cv = catval + (size_t)catrowS[1][ii] * 768;
#pragma unroll
      for (int ch = 0; ch < 3; ch++) {
        floatx4 v = *(const floatx4*)(cv + ch * 256 + dl);
#pragma unroll
        for (int q = 0; q < 4; q++) accB[ch * 4 + q] = __builtin_fmaf(wr, v[q], accB[ch * 4 + q]);
      }
    }
  }
  if (lane == 0) { kbw[0][wv] = kbA; kbw[1][wv] = kbB; }

  const float sb0 = sgu_b[0];

  // epilogue b0
#pragma unroll
  for (int ch = 0; ch < 3; ch++)
    *(floatx4*)&accw[wv][ch * 256 + dl] = *(const floatx4*)&accA[ch * 4];
  __syncthreads();
  {
    float kbs = 0.f;
#pragma unroll
    for (int w = 0; w < 8; w++) kbs += kbw[0][w];
#pragma unroll
    for (int i = 0; i < 21; i++) kbs += catkb[0][i];
    const float wss = wss_s;
    for (int d = tid; d < 704; d += 512) {
      unsigned short o = 0;
      if (d < 675) {
        float a = 0.f;
#pragma unroll
        for (int w = 0; w < 8; w++) a += accw[w][d];
        const float v0 = sgu_ln_g[d] * (a - kbs) + sgu_ln_b[d] * wss + sb0;
        o = f2bf(ucon[d] * v0);
      }
      uv[(size_t)b0 * 704 + d] = o;
    }
  }
  __syncthreads();
  // epilogue b1
#pragma unroll
  for (int ch = 0; ch < 3; ch++)
    *(floatx4*)&accw[wv][ch * 256 + dl] = *(const floatx4*)&accB[ch * 4];
  __syncthreads();
  {
    float kbs = 0.f;
#pragma unroll
    for (int w = 0; w < 8; w++) kbs += kbw[1][w];
#pragma unroll
    for (int i = 0; i < 21; i++) kbs += catkb[1][i];
    const float wss = wss_s;
    for (int d = tid; d < 704; d += 512) {
      unsigned short o = 0;
      if (d < 675) {
        float a = 0.f;
#pragma unroll
        for (int w = 0; w < 8; w++) a += accw[w][d];
        const float v0 = sgu_ln_g[d] * (a - kbs) + sgu_ln_b[d] * wss + sb0;
        o = f2bf(ucon[d] * v0);
      }
      uv[(size_t)b1 * 704 + d] = o;
    }
  }
}

// ---------------- LN + gelu -> hidden (f32 + bf16) ----------------
__global__ __launch_bounds__(256)
void ln_gelu_hidden(const float* __restrict__ xfin,
                    const float* __restrict__ ln_g, const float* __restrict__ ln_b,
                    float* __restrict__ hid_f, unsigned short* __restrict__ hid_bf)
{
  const int w = (blockIdx.x * 256 + threadIdx.x) >> 6;
  const int lane = threadIdx.x & 63;
  if (w >= B_SZ) return;
  const float* row = xfin + (size_t)w * 1024;
  float s = 0.f, ss = 0.f;
  for (int k = lane; k < 1024; k += 64) { float v = row[k]; s += v; ss += v * v; }
  s = wred(s); ss = wred(ss);
  const float m = s * (1.f / 1024.f);
  const float var = ss * (1.f / 1024.f) - m * m;
  const float rs = rsqrtf(var + 1e-5f);
  for (int k = lane; k < 1024; k += 64) {
    float v = gelu_exact((row[k] - m) * rs * ln_g[k] + ln_b[k]);
    hid_f[(size_t)w * 1024 + k] = v;
    hid_bf[(size_t)w * 1024 + k] = f2bf(v);
  }
}

// ---------------- per-row finale ----------------
__global__ __launch_bounds__(256)
void final_head(const unsigned short* __restrict__ H1, const float* __restrict__ hid_f,
                const float* __restrict__ r_w2, const float* __restrict__ r_b2,
                const float* __restrict__ a_w2, const float* __restrict__ a_b2,
                const float* __restrict__ gh_w2, const float* __restrict__ gh_b2,
                const float* __restrict__ ex_w2, const float* __restrict__ ex_b2,
                const float* __restrict__ base_w, const float* __restrict__ base_b,
                float* __restrict__ out)
{
  const int b = blockIdx.x;
  const int tid = threadIdx.x;
  const unsigned short* h1 = H1 + (size_t)b * 3072;
  float p[11];
#pragma unroll
  for (int i = 0; i < 11; i++) p[i] = 0.f;
  {
    const int m = tid;
    const float hr = bf2f(h1[m]);
    p[0] = hr * r_w2[m * 4 + 0];
    p[1] = hr * r_w2[m * 4 + 1];
    p[2] = hr * r_w2[m * 4 + 2];
    p[3] = hr * r_w2[m * 4 + 3];
    const float ha = bf2f(h1[256 + m]);
    p[4] = ha * a_w2[m];
  }
  for (int m = tid; m < 512; m += 256) {
    p[5] += bf2f(h1[512 + m]) * gh_w2[m];
#pragma unroll
    for (int e = 0; e < 4; e++)
      p[6 + e] += bf2f(h1[1024 + e * 512 + m]) * ex_w2[e * 512 + m];
  }
  for (int k = tid; k < 1024; k += 256) p[10] += hid_f[(size_t)b * 1024 + k] * base_w[k];

  __shared__ float red[11][4];
  const int lane = tid & 63, wv = tid >> 6;
#pragma unroll
  for (int i = 0; i < 11; i++) {
    const float v = wred(p[i]);
    if (lane == 0) red[i][wv] = v;
  }
  __syncthreads();
  if (tid == 0) {
    float s[11];
#pragma unroll
    for (int i = 0; i < 11; i++) s[i] = red[i][0] + red[i][1] + red[i][2] + red[i][3];
    float lg[4];
#pragma unroll
    for (int e = 0; e < 4; e++) lg[e] = s[e] + r_b2[e];
    const float mx = fmaxf(fmaxf(lg[0], lg[1]), fmaxf(lg[2], lg[3]));
    float den[4]; float dsum = 0.f;
#pragma unroll
    for (int e = 0; e < 4; e++) { den[e] = expf(lg[e] - mx); dsum += den[e]; }
#pragma unroll
    for (int e = 0; e < 4; e++) den[e] /= dsum;
    int i1 = 0;
    for (int e = 1; e < 4; e++) if (den[e] > den[i1]) i1 = e;
    int i2 = -1;
    for (int e = 0; e < 4; e++) { if (e == i1) continue; if (i2 < 0 || den[e] > den[i2]) i2 = e; }
    float eo[4];
#pragma unroll
    for (int e = 0; e < 4; e++) eo[e] = s[6 + e] + ex_b2[e];
    const float v1 = den[i1], v2 = den[i2];
    const float ssum = fmaxf(v1 + v2, 1e-8f);
    const float local = (v1 * eo[i1] + v2 * eo[i2]) / ssum;
    const float glob = s[5] + gh_b2[0];
    const float alpha = 1.0f / (1.0f + expf(-(s[4] + a_b2[0])));
    out[b] = s[10] + base_b[0] + alpha * (glob + local);
  }
}

extern "C" void kernel_launch(void* const* d_in, const int* in_sizes, int n_in,
                              void* d_out, int out_size, void* d_ws, size_t ws_size,
                              hipStream_t stream)
{
  const float* x_num  = (const float*)d_in[0];
  const int*   x_cat  = (const int*)d_in[1];
  const float* tok_w  = (const float*)d_in[2];
  const float* tok_b  = (const float*)d_in[3];
  const float* cat_emb= (const float*)d_in[4];
  const float* ln_g   = (const float*)d_in[5];
  const float* ln_b   = (const float*)d_in[6];
  const float* lin0_w = (const float*)d_in[7];
  const float* lin0_b = (const float*)d_in[8];
  const float* sgu_ln_g = (const float*)d_in[9];
  const float* sgu_ln_b = (const float*)d_in[10];
  const float* sgu_w  = (const float*)d_in[11];
  const float* sgu_b  = (const float*)d_in[12];
  const float* lin1_w = (const float*)d_in[13];
  const float* lin1_b = (const float*)d_in[14];
  const float* r_w1   = (const float*)d_in[15];
  const float* r_b1   = (const float*)d_in[16];
  const float* r_w2   = (const float*)d_in[17];
  const float* r_b2   = (const float*)d_in[18];
  const float* a_w1   = (const float*)d_in[19];
  const float* a_b1   = (const float*)d_in[20];
  const float* a_w2   = (const float*)d_in[21];
  const float* a_b2   = (const float*)d_in[22];
  const float* base_w = (const float*)d_in[23];
  const float* base_b = (const float*)d_in[24];
  const float* gh_w1  = (const float*)d_in[25];
  const float* gh_b1  = (const float*)d_in[26];
  const float* gh_w2  = (const float*)d_in[27];
  const float* gh_b2  = (const float*)d_in[28];
  const float* ex_w1  = (const float*)d_in[29];
  const float* ex_b1  = (const float*)d_in[30];
  const float* ex_w2  = (const float*)d_in[31];
  const float* ex_b2  = (const float*)d_in[32];
  (void)in_sizes; (void)n_in; (void)out_size; (void)ws_size;

  char* ws = (char*)d_ws;
  size_t off = 0;
  auto alloc = [&](size_t bytes) { void* p = ws + off; off += (bytes + 255) & ~(size_t)255; return p; };

  unsigned short* w0v  = (unsigned short*)alloc((size_t)768 * 1024 * 2);
  unsigned short* w0u  = (unsigned short*)alloc((size_t)768 * 1024 * 2);
  unsigned short* w1t  = (unsigned short*)alloc((size_t)1024 * 704 * 2);
  unsigned short* wcat = (unsigned short*)alloc((size_t)3072 * 1024 * 2);
  float* bcat          = (float*)alloc((size_t)3072 * 4);
  unsigned short* Amat = (unsigned short*)alloc((size_t)2304 * 1024 * 2);
  float* TAB           = (float*)alloc((size_t)2304 * 768 * 4);
  float* nstat         = (float*)alloc((size_t)101 * 5 * 4);
  float* cstat         = (float*)alloc((size_t)2000 * 2 * 4);
  float* catval        = (float*)alloc((size_t)2001 * 768 * 4);
  float* catsc         = (float*)alloc((size_t)2001 * 2 * 4);
  float* ucon          = (float*)alloc((size_t)704 * 4);
  unsigned short* uv   = (unsigned short*)alloc((size_t)B_SZ * 704 * 2);
  float* xfin          = (float*)alloc((size_t)B_SZ * 1024 * 4);
  float* hid_f         = (float*)alloc((size_t)B_SZ * 1024 * 4);
  unsigned short* hidb = (unsigned short*)alloc((size_t)B_SZ * 1024 * 2);
  unsigned short* H1   = (unsigned short*)alloc((size_t)B_SZ * 3072 * 2);

  const dim3 blk(256);

  PrepArgs J;
  auto setJ = [&](int i, const float* s, unsigned short* d, int ldin, int coff,
                  int Nsrc, int Ksrc, int Kp, int nbx, int nby) {
    J.src[i] = s; J.dst[i] = d; J.ldin[i] = ldin; J.coff[i] = coff;
    J.Nsrc[i] = Nsrc; J.Ksrc[i] = Ksrc; J.Kp[i] = Kp; J.nbx[i] = nbx;
    J.blk0[i + 1] = J.blk0[i] + nbx * nby;
  };
  J.blk0[0] = 0;
  setJ(0, lin0_w, w0v, 1350, 675, 675, 1024, 1024, 16, 12);
  setJ(1, lin0_w, w0u, 1350, 0,   675, 1024, 1024, 16, 12);
  setJ(2, lin1_w, w1t, 1024, 0,  1024,  675,  704, 11, 16);
  setJ(3, r_w1,  wcat,                          256, 0, 256, 1024, 1024, 16, 4);
  setJ(4, a_w1,  wcat + (size_t)256 * 1024,     256, 0, 256, 1024, 1024, 16, 4);
  setJ(5, gh_w1, wcat + (size_t)512 * 1024,     512, 0, 512, 1024, 1024, 16, 8);
  for (int e = 0; e < 4; e++)
    setJ(6 + e, ex_w1 + (size_t)e * 1024 * 512,
         wcat + (size_t)(1024 + e * 512) * 1024, 512, 0, 512, 1024, 1024, 16, 8);

  const int nprep = J.blk0[10] + 576 + 526 + 12;   // 2442
  prep_all<<<nprep, blk, 0, stream>>>(J, tok_w, tok_b, cat_emb, ln_g, ln_b,
      r_b1, a_b1, gh_b1, ex_b1, Amat, nstat, cstat, bcat);

  tab_and_u<<<284, blk, 0, stream>>>(Amat, w0v, TAB, w0u, nstat, tok_w, ln_g, ln_b, lin0_b, ucon);

  cat_rows<<<501, blk, 0, stream>>>(TAB, nstat, cstat, lin0_b, catval, catsc);

  fused_v2<<<512, dim3(512), 0, stream>>>(TAB, nstat, catsc, catval, x_num, x_cat,
      sgu_ln_g, sgu_ln_b, sgu_w, sgu_b, lin0_b, ucon, uv);

  gemm_gl<0><<<8 * 8, blk, 0, stream>>>(uv, 704, w1t, 704,
      lin1_b, 0, tok_w, 8, 1024, 1024, xfin, nullptr);
  ln_gelu_hidden<<<B_SZ / 4, blk, 0, stream>>>(xfin, ln_g, ln_b, hid_f, hidb);
  gemm_gl<1><<<8 * 24, blk, 0, stream>>>(hidb, 1024, wcat, 1024,
      bcat, 0, nullptr, 24, 3072, 3072, nullptr, H1);

  final_head<<<B_SZ, blk, 0, stream>>>(H1, hid_f, r_w2, r_b2, a_w2, a_b2, gh_w2, gh_b2,
                                       ex_w2, ex_b2, base_w, base_b, (float*)d_out);
}